// Round 1
// baseline (5830.011 us; speedup 1.0000x reference)
//
#include <hip/hip_runtime.h>
#include <hip/hip_bf16.h>

// Problem constants (validated/derived from in_sizes where cheap)
#define IN_DIM 64
#define H_DIM 128
#define L_LAYERS 3
#define G_GRAPHS 256
#define C_CLASSES 10

// ---------------------------------------------------------------------------
// CSR build: deg count -> block scan -> scan of block sums -> finalize -> scatter
// ---------------------------------------------------------------------------
__global__ void count_deg(const int* __restrict__ dst, int* __restrict__ deg, int e) {
    int i = blockIdx.x * blockDim.x + threadIdx.x;
    if (i < e) atomicAdd(&deg[dst[i]], 1);
}

__global__ __launch_bounds__(256) void scan1(const int* __restrict__ deg,
                                             int* __restrict__ rowptr,
                                             int* __restrict__ bsum, int n) {
    int i = blockIdx.x * 256 + threadIdx.x;
    int v = (i < n) ? deg[i] : 0;
    __shared__ int sm[256];
    sm[threadIdx.x] = v;
    __syncthreads();
    for (int off = 1; off < 256; off <<= 1) {
        int x = (threadIdx.x >= off) ? sm[threadIdx.x - off] : 0;
        __syncthreads();
        sm[threadIdx.x] += x;
        __syncthreads();
    }
    if (i < n) rowptr[i + 1] = sm[threadIdx.x];
    if (threadIdx.x == 255) bsum[blockIdx.x] = sm[255];
}

__global__ __launch_bounds__(512) void scan2(int* __restrict__ bsum, int nblk) {
    __shared__ int sm[512];
    int t = threadIdx.x;
    int v = (t < nblk) ? bsum[t] : 0;
    sm[t] = v;
    __syncthreads();
    for (int off = 1; off < 512; off <<= 1) {
        int x = (t >= off) ? sm[t - off] : 0;
        __syncthreads();
        sm[t] += x;
        __syncthreads();
    }
    if (t < nblk) bsum[t] = sm[t] - v;  // exclusive
}

__global__ void scan3(int* __restrict__ rowptr, int* __restrict__ wpos,
                      const int* __restrict__ bsum, const int* __restrict__ deg, int n) {
    int i = blockIdx.x * 256 + threadIdx.x;
    if (i < n) {
        int incl = rowptr[i + 1] + bsum[i >> 8];
        rowptr[i + 1] = incl;
        wpos[i] = incl - deg[i];   // start of bucket i
    }
    if (i == 0) rowptr[0] = 0;
}

__global__ void scatter_edges(const int* __restrict__ src, const int* __restrict__ dst,
                              int* __restrict__ wpos, int* __restrict__ esrc, int e) {
    int i = blockIdx.x * blockDim.x + threadIdx.x;
    if (i < e) {
        int pos = atomicAdd(&wpos[dst[i]], 1);
        esrc[pos] = src[i];
    }
}

// ---------------------------------------------------------------------------
// Fused Q/K/V/Skip GEMM: out = X @ W + b for 4 weights (blockIdx.y selects).
// Tile 128 rows x 128 cols, K-tiles of 64, 8x8 per thread, fp32 vector FMA.
// ---------------------------------------------------------------------------
template <int K>
__global__ __launch_bounds__(256) void gemm_qkvs(
    const float* __restrict__ X, int n,
    const float* __restrict__ W0, const float* __restrict__ b0,
    const float* __restrict__ W1, const float* __restrict__ b1,
    const float* __restrict__ W2, const float* __restrict__ b2,
    const float* __restrict__ W3, const float* __restrict__ b3,
    float* __restrict__ o0, float* __restrict__ o1,
    float* __restrict__ o2, float* __restrict__ o3) {
    const float* W; const float* bias; float* out;
    switch (blockIdx.y) {
        case 0:  W = W0; bias = b0; out = o0; break;
        case 1:  W = W1; bias = b1; out = o1; break;
        case 2:  W = W2; bias = b2; out = o2; break;
        default: W = W3; bias = b3; out = o3; break;
    }
    __shared__ float Xs[64][132];  // [kk][row], transposed; 132 keeps float4 align + spreads banks
    __shared__ float Wt[64][132];  // [kk][col]
    const int t = threadIdx.x;
    const int tx = t & 15, ty = t >> 4;
    const int row0 = blockIdx.x * 128;

    float acc[8][8];
#pragma unroll
    for (int i = 0; i < 8; ++i)
#pragma unroll
        for (int j = 0; j < 8; ++j) acc[i][j] = 0.f;

    for (int kt = 0; kt < K; kt += 64) {
        // stage X^T (128 rows x 64 k) — zero-pad OOB rows
        {
            int r = t >> 4;            // 0..15
            int c4 = (t & 15) * 4;     // 0..60
#pragma unroll
            for (int p = 0; p < 8; ++p) {
                int row = row0 + p * 16 + r;
                float4 xv = make_float4(0.f, 0.f, 0.f, 0.f);
                if (row < n) xv = *(const float4*)(X + (size_t)row * K + kt + c4);
                Xs[c4 + 0][p * 16 + r] = xv.x;
                Xs[c4 + 1][p * 16 + r] = xv.y;
                Xs[c4 + 2][p * 16 + r] = xv.z;
                Xs[c4 + 3][p * 16 + r] = xv.w;
            }
            // stage W (64 k x 128 cols)
            int kr = t >> 5;           // 0..7
            int wc4 = (t & 31) * 4;    // 0..124
#pragma unroll
            for (int p = 0; p < 8; ++p) {
                int kk = p * 8 + kr;
                float4 wv = *(const float4*)(W + (size_t)(kt + kk) * 128 + wc4);
                *(float4*)(&Wt[kk][wc4]) = wv;
            }
        }
        __syncthreads();
#pragma unroll
        for (int kk = 0; kk < 64; ++kk) {
            float a[8], b[8];
            *(float4*)(a)     = *(const float4*)(&Xs[kk][ty * 8]);
            *(float4*)(a + 4) = *(const float4*)(&Xs[kk][ty * 8 + 4]);
            *(float4*)(b)     = *(const float4*)(&Wt[kk][tx * 8]);
            *(float4*)(b + 4) = *(const float4*)(&Wt[kk][tx * 8 + 4]);
#pragma unroll
            for (int i = 0; i < 8; ++i)
#pragma unroll
                for (int j = 0; j < 8; ++j) acc[i][j] = fmaf(a[i], b[j], acc[i][j]);
        }
        __syncthreads();
    }
#pragma unroll
    for (int i = 0; i < 8; ++i) {
        int row = row0 + ty * 8 + i;
        if (row >= n) continue;
#pragma unroll
        for (int j4 = 0; j4 < 2; ++j4) {
            int c = tx * 8 + j4 * 4;
            float4 r;
            r.x = acc[i][j4 * 4 + 0] + bias[c + 0];
            r.y = acc[i][j4 * 4 + 1] + bias[c + 1];
            r.z = acc[i][j4 * 4 + 2] + bias[c + 2];
            r.w = acc[i][j4 * 4 + 3] + bias[c + 3];
            *(float4*)(out + (size_t)row * 128 + c) = r;
        }
    }
}

// ---------------------------------------------------------------------------
// Per-target edge attention with online softmax. One wave per target node.
// h2 (pre-filled with x@Ws + bs) gets += softmax-weighted sum of v[src].
// ---------------------------------------------------------------------------
__global__ __launch_bounds__(256) void attn_kernel(
    const float* __restrict__ q, const float* __restrict__ k, const float* __restrict__ v,
    const int* __restrict__ rowptr, const int* __restrict__ esrc,
    float* __restrict__ h2, int n) {
    int wid = (blockIdx.x * blockDim.x + threadIdx.x) >> 6;
    int lane = threadIdx.x & 63;
    if (wid >= n) return;
    int f0 = lane * 2;
    float2 qv = *(const float2*)(q + (size_t)wid * 128 + f0);
    const float scale = 0.08838834764831845f;  // 1/sqrt(128)
    int beg = rowptr[wid], end = rowptr[wid + 1];
    float m = -3.402823466e38f, ssum = 0.f, acc0 = 0.f, acc1 = 0.f;
    for (int j = beg; j < end; ++j) {
        int s = esrc[j];
        float2 kv = *(const float2*)(k + (size_t)s * 128 + f0);
        float d = qv.x * kv.x + qv.y * kv.y;
#pragma unroll
        for (int off = 32; off; off >>= 1) d += __shfl_xor(d, off);
        d *= scale;
        float2 vv = *(const float2*)(v + (size_t)s * 128 + f0);
        if (d > m) {   // uniform across wave (d is wave-reduced)
            float r = __expf(m - d);  // first iter: exp(-huge) = 0
            ssum *= r; acc0 *= r; acc1 *= r; m = d;
        }
        float w = __expf(d - m);
        ssum += w;
        acc0 += w * vv.x;
        acc1 += w * vv.y;
    }
    if (ssum > 0.f) {
        float inv = 1.f / ssum;
        float2* o = (float2*)(h2 + (size_t)wid * 128 + f0);
        float2 cur = *o;
        cur.x += acc0 * inv;
        cur.y += acc1 * inv;
        *o = cur;
    }
}

// ---------------------------------------------------------------------------
// BatchNorm (training stats) + ReLU
// ---------------------------------------------------------------------------
__global__ __launch_bounds__(256) void bn_stats(const float* __restrict__ h2,
                                                float* __restrict__ psum,
                                                float* __restrict__ psq, int n) {
    int f = threadIdx.x & 127;
    int rp = threadIdx.x >> 7;  // 0..1
    float s = 0.f, s2 = 0.f;
    for (int r = blockIdx.x * 2 + rp; r < n; r += gridDim.x * 2) {
        float x = h2[(size_t)r * 128 + f];
        s += x;
        s2 += x * x;
    }
    __shared__ float sm[256], sm2[256];
    sm[threadIdx.x] = s;
    sm2[threadIdx.x] = s2;
    __syncthreads();
    if (rp == 0) {
        psum[blockIdx.x * 128 + f] = sm[f] + sm[128 + f];
        psq[blockIdx.x * 128 + f] = sm2[f] + sm2[128 + f];
    }
}

__global__ void bn_finalize(const float* __restrict__ psum, const float* __restrict__ psq,
                            const float* __restrict__ g, const float* __restrict__ b,
                            float* __restrict__ scale, float* __restrict__ shift,
                            int n, int nblk) {
    int f = threadIdx.x;  // 128 threads
    float s = 0.f, s2 = 0.f;
    for (int i = 0; i < nblk; ++i) {
        s += psum[i * 128 + f];
        s2 += psq[i * 128 + f];
    }
    float inv_n = 1.f / (float)n;
    float mu = s * inv_n;
    float var = s2 * inv_n - mu * mu;
    float sc = g[f] * rsqrtf(var + 1e-5f);
    scale[f] = sc;
    shift[f] = b[f] - mu * sc;
}

__global__ __launch_bounds__(256) void bn_apply_relu(const float* __restrict__ h2,
                                                     const float* __restrict__ scale,
                                                     const float* __restrict__ shift,
                                                     float* __restrict__ h, int total4) {
    int i = blockIdx.x * blockDim.x + threadIdx.x;
    if (i >= total4) return;
    float4 x = ((const float4*)h2)[i];
    int f = (i * 4) & 127;
    x.x = fmaxf(0.f, x.x * scale[f + 0] + shift[f + 0]);
    x.y = fmaxf(0.f, x.y * scale[f + 1] + shift[f + 1]);
    x.z = fmaxf(0.f, x.z * scale[f + 2] + shift[f + 2]);
    x.w = fmaxf(0.f, x.w * scale[f + 3] + shift[f + 3]);
    ((float4*)h)[i] = x;
}

// ---------------------------------------------------------------------------
// Pool (batch is sorted -> per-graph contiguous row range via binary search)
// and classifier head.
// ---------------------------------------------------------------------------
__global__ __launch_bounds__(256) void pool_kernel(const float* __restrict__ h,
                                                   const int* __restrict__ batch,
                                                   float* __restrict__ pooled, int n) {
    int g = blockIdx.x;
    int lo = 0, hi = n;
    while (lo < hi) { int mid = (lo + hi) >> 1; if (batch[mid] < g) lo = mid + 1; else hi = mid; }
    int start = lo;
    lo = start; hi = n;
    while (lo < hi) { int mid = (lo + hi) >> 1; if (batch[mid] < g + 1) lo = mid + 1; else hi = mid; }
    int end = lo;
    int f = threadIdx.x & 127, rp = threadIdx.x >> 7;
    float s = 0.f;
    for (int r = start + rp; r < end; r += 2) s += h[(size_t)r * 128 + f];
    __shared__ float sm[256];
    sm[threadIdx.x] = s;
    __syncthreads();
    if (rp == 0) {
        float tot = sm[f] + sm[128 + f];
        float cnt = (float)(end - start);
        pooled[g * 128 + f] = tot / fmaxf(cnt, 1.f);
    }
}

__global__ void head_kernel(const float* __restrict__ pooled, const float* __restrict__ W,
                            const float* __restrict__ bias, float* __restrict__ out) {
    int g = blockIdx.x;
    int lane = threadIdx.x;  // 64
    float p0 = pooled[g * 128 + lane];
    float p1 = pooled[g * 128 + 64 + lane];
#pragma unroll
    for (int c = 0; c < C_CLASSES; ++c) {
        float d = p0 * W[lane * C_CLASSES + c] + p1 * W[(64 + lane) * C_CLASSES + c];
#pragma unroll
        for (int off = 32; off; off >>= 1) d += __shfl_xor(d, off);
        if (lane == 0) out[g * C_CLASSES + c] = d + bias[c];
    }
}

// ---------------------------------------------------------------------------
extern "C" void kernel_launch(void* const* d_in, const int* in_sizes, int n_in,
                              void* d_out, int out_size, void* d_ws, size_t ws_size,
                              hipStream_t stream) {
    const int N = in_sizes[0] / IN_DIM;       // 100000
    const int E = in_sizes[1] / 2;            // 600000

    const float* x     = (const float*)d_in[0];
    const int* ei      = (const int*)d_in[1];
    const int* src     = ei;
    const int* dst     = ei + E;
    const int* batch   = (const int*)d_in[2];
    const float* Wq1 = (const float*)d_in[3],  *bq1 = (const float*)d_in[4];
    const float* Wk1 = (const float*)d_in[5],  *bk1 = (const float*)d_in[6];
    const float* Wv1 = (const float*)d_in[7],  *bv1 = (const float*)d_in[8];
    const float* Ws1 = (const float*)d_in[9],  *bs1 = (const float*)d_in[10];
    const float* bn1g = (const float*)d_in[11], *bn1b = (const float*)d_in[12];
    const float* Wq = (const float*)d_in[13], *bq = (const float*)d_in[14];
    const float* Wk = (const float*)d_in[15], *bk = (const float*)d_in[16];
    const float* Wv = (const float*)d_in[17], *bv = (const float*)d_in[18];
    const float* Ws = (const float*)d_in[19], *bs = (const float*)d_in[20];
    const float* bng = (const float*)d_in[21], *bnb = (const float*)d_in[22];
    const float* linW = (const float*)d_in[23], *linb = (const float*)d_in[24];
    float* out = (float*)d_out;

    // workspace layout
    char* w = (char*)d_ws;
    auto alloc = [&](size_t bytes) -> char* {
        char* p = w;
        w += (bytes + 255) & ~(size_t)255;
        return p;
    };
    const size_t NH = (size_t)N * H_DIM;
    float* q    = (float*)alloc(NH * 4);
    float* kbuf = (float*)alloc(NH * 4);
    float* vbuf = (float*)alloc(NH * 4);
    float* hB   = (float*)alloc(NH * 4);   // h2 (conv output pre-BN)
    float* hA   = (float*)alloc(NH * 4);   // activations post BN+ReLU
    float* psum = (float*)alloc(256 * 128 * 4);
    float* psq  = (float*)alloc(256 * 128 * 4);
    float* bnsc = (float*)alloc(128 * 4);
    float* bnsh = (float*)alloc(128 * 4);
    float* pooled = (float*)alloc(G_GRAPHS * H_DIM * 4);
    int* deg    = (int*)alloc((size_t)N * 4);
    int* rowptr = (int*)alloc((size_t)(N + 1) * 4);
    int* wpos   = (int*)alloc((size_t)N * 4);
    int* esrc   = (int*)alloc((size_t)E * 4);
    int* bsum   = (int*)alloc(((size_t)(N + 255) / 256) * 4);

    const int nblk = (N + 255) / 256;        // 391
    const int egrid = (E + 255) / 256;

    // ---- CSR build (per call; ws is re-poisoned between launches)
    hipMemsetAsync(deg, 0, (size_t)N * 4, stream);
    count_deg<<<egrid, 256, 0, stream>>>(dst, deg, E);
    scan1<<<nblk, 256, 0, stream>>>(deg, rowptr, bsum, N);
    scan2<<<1, 512, 0, stream>>>(bsum, nblk);
    scan3<<<nblk, 256, 0, stream>>>(rowptr, wpos, bsum, deg, N);
    scatter_edges<<<egrid, 256, 0, stream>>>(src, dst, wpos, esrc, E);

    const int gx = (N + 127) / 128;          // 782
    const int attn_blocks = (N + 3) / 4;     // 4 waves/block
    const int ew4 = (int)(NH / 4);
    const int ew4_grid = (ew4 + 255) / 256;

    // ---- layer 1 (IN=64)
    gemm_qkvs<IN_DIM><<<dim3(gx, 4), 256, 0, stream>>>(
        x, N, Wq1, bq1, Wk1, bk1, Wv1, bv1, Ws1, bs1, q, kbuf, vbuf, hB);
    attn_kernel<<<attn_blocks, 256, 0, stream>>>(q, kbuf, vbuf, rowptr, esrc, hB, N);
    bn_stats<<<256, 256, 0, stream>>>(hB, psum, psq, N);
    bn_finalize<<<1, 128, 0, stream>>>(psum, psq, bn1g, bn1b, bnsc, bnsh, N, 256);
    bn_apply_relu<<<ew4_grid, 256, 0, stream>>>(hB, bnsc, bnsh, hA, ew4);

    // ---- layers 2..4 (H=128)
    for (int i = 0; i < L_LAYERS; ++i) {
        const size_t wo = (size_t)i * H_DIM * H_DIM;
        const size_t bo = (size_t)i * H_DIM;
        gemm_qkvs<H_DIM><<<dim3(gx, 4), 256, 0, stream>>>(
            hA, N, Wq + wo, bq + bo, Wk + wo, bk + bo, Wv + wo, bv + bo,
            Ws + wo, bs + bo, q, kbuf, vbuf, hB);
        attn_kernel<<<attn_blocks, 256, 0, stream>>>(q, kbuf, vbuf, rowptr, esrc, hB, N);
        bn_stats<<<256, 256, 0, stream>>>(hB, psum, psq, N);
        bn_finalize<<<1, 128, 0, stream>>>(psum, psq, bng + bo, bnb + bo, bnsc, bnsh, N, 256);
        bn_apply_relu<<<ew4_grid, 256, 0, stream>>>(hB, bnsc, bnsh, hA, ew4);
    }

    // ---- pool + head
    pool_kernel<<<G_GRAPHS, 256, 0, stream>>>(hA, batch, pooled, N);
    head_kernel<<<G_GRAPHS, 64, 0, stream>>>(pooled, linW, linb, out);
}

// Round 2
// 5416.093 us; speedup vs baseline: 1.0764x; 1.0764x over previous
//
#include <hip/hip_runtime.h>
#include <hip/hip_bf16.h>

// Problem constants
#define IN_DIM 64
#define H_DIM 128
#define L_LAYERS 3
#define G_GRAPHS 256
#define C_CLASSES 10

// ---------------------------------------------------------------------------
// CSR build: deg count -> block scan -> scan of block sums -> finalize -> scatter
// ---------------------------------------------------------------------------
__global__ void count_deg(const int* __restrict__ dst, int* __restrict__ deg, int e) {
    int i = blockIdx.x * blockDim.x + threadIdx.x;
    if (i < e) atomicAdd(&deg[dst[i]], 1);
}

__global__ __launch_bounds__(256) void scan1(const int* __restrict__ deg,
                                             int* __restrict__ rowptr,
                                             int* __restrict__ bsum, int n) {
    int i = blockIdx.x * 256 + threadIdx.x;
    int v = (i < n) ? deg[i] : 0;
    __shared__ int sm[256];
    sm[threadIdx.x] = v;
    __syncthreads();
    for (int off = 1; off < 256; off <<= 1) {
        int x = (threadIdx.x >= off) ? sm[threadIdx.x - off] : 0;
        __syncthreads();
        sm[threadIdx.x] += x;
        __syncthreads();
    }
    if (i < n) rowptr[i + 1] = sm[threadIdx.x];
    if (threadIdx.x == 255) bsum[blockIdx.x] = sm[255];
}

__global__ __launch_bounds__(512) void scan2(int* __restrict__ bsum, int nblk) {
    __shared__ int sm[512];
    int t = threadIdx.x;
    int v = (t < nblk) ? bsum[t] : 0;
    sm[t] = v;
    __syncthreads();
    for (int off = 1; off < 512; off <<= 1) {
        int x = (t >= off) ? sm[t - off] : 0;
        __syncthreads();
        sm[t] += x;
        __syncthreads();
    }
    if (t < nblk) bsum[t] = sm[t] - v;  // exclusive
}

__global__ void scan3(int* __restrict__ rowptr, int* __restrict__ wpos,
                      const int* __restrict__ bsum, const int* __restrict__ deg, int n) {
    int i = blockIdx.x * 256 + threadIdx.x;
    if (i < n) {
        int incl = rowptr[i + 1] + bsum[i >> 8];
        rowptr[i + 1] = incl;
        wpos[i] = incl - deg[i];   // start of bucket i
    }
    if (i == 0) rowptr[0] = 0;
}

__global__ void scatter_edges(const int* __restrict__ src, const int* __restrict__ dst,
                              int* __restrict__ wpos, int* __restrict__ esrc, int e) {
    int i = blockIdx.x * blockDim.x + threadIdx.x;
    if (i < e) {
        int pos = atomicAdd(&wpos[dst[i]], 1);
        esrc[pos] = src[i];
    }
}

// ---------------------------------------------------------------------------
// Fused Q/K/V/Skip GEMM: out = act(X) @ W + b for 4 weights (blockIdx.y selects).
// If BN: act(x) = relu(x*bnsc + bnsh) applied while staging X (fuses the
// previous layer's BatchNorm+ReLU into this GEMM's read — free, memory-side).
// Tile 128 rows x 128 cols, K-tiles of 64, 8x8 per thread, fp32 vector FMA.
// ---------------------------------------------------------------------------
template <int K, bool BN>
__global__ __launch_bounds__(256) void gemm_qkvs(
    const float* __restrict__ X, int n,
    const float* __restrict__ bnsc, const float* __restrict__ bnsh,
    const float* __restrict__ W0, const float* __restrict__ b0,
    const float* __restrict__ W1, const float* __restrict__ b1,
    const float* __restrict__ W2, const float* __restrict__ b2,
    const float* __restrict__ W3, const float* __restrict__ b3,
    float* __restrict__ o0, float* __restrict__ o1,
    float* __restrict__ o2, float* __restrict__ o3) {
    const float* W; const float* bias; float* out;
    switch (blockIdx.y) {
        case 0:  W = W0; bias = b0; out = o0; break;
        case 1:  W = W1; bias = b1; out = o1; break;
        case 2:  W = W2; bias = b2; out = o2; break;
        default: W = W3; bias = b3; out = o3; break;
    }
    __shared__ float Xs[64][132];  // [kk][row], transposed
    __shared__ float Wt[64][132];  // [kk][col]
    const int t = threadIdx.x;
    const int tx = t & 15, ty = t >> 4;
    const int row0 = blockIdx.x * 128;

    float acc[8][8];
#pragma unroll
    for (int i = 0; i < 8; ++i)
#pragma unroll
        for (int j = 0; j < 8; ++j) acc[i][j] = 0.f;

    for (int kt = 0; kt < K; kt += 64) {
        {
            int r = t >> 4;            // 0..15
            int c4 = (t & 15) * 4;     // 0..60
            float4 sc4, sh4;
            if (BN) {
                sc4 = *(const float4*)(bnsc + kt + c4);
                sh4 = *(const float4*)(bnsh + kt + c4);
            }
#pragma unroll
            for (int p = 0; p < 8; ++p) {
                int row = row0 + p * 16 + r;
                float4 xv = make_float4(0.f, 0.f, 0.f, 0.f);
                if (row < n) {
                    xv = *(const float4*)(X + (size_t)row * K + kt + c4);
                    if (BN) {
                        xv.x = fmaxf(0.f, fmaf(xv.x, sc4.x, sh4.x));
                        xv.y = fmaxf(0.f, fmaf(xv.y, sc4.y, sh4.y));
                        xv.z = fmaxf(0.f, fmaf(xv.z, sc4.z, sh4.z));
                        xv.w = fmaxf(0.f, fmaf(xv.w, sc4.w, sh4.w));
                    }
                }
                Xs[c4 + 0][p * 16 + r] = xv.x;
                Xs[c4 + 1][p * 16 + r] = xv.y;
                Xs[c4 + 2][p * 16 + r] = xv.z;
                Xs[c4 + 3][p * 16 + r] = xv.w;
            }
            int kr = t >> 5;           // 0..7
            int wc4 = (t & 31) * 4;    // 0..124
#pragma unroll
            for (int p = 0; p < 8; ++p) {
                int kk = p * 8 + kr;
                float4 wv = *(const float4*)(W + (size_t)(kt + kk) * 128 + wc4);
                *(float4*)(&Wt[kk][wc4]) = wv;
            }
        }
        __syncthreads();
#pragma unroll
        for (int kk = 0; kk < 64; ++kk) {
            float a[8], b[8];
            *(float4*)(a)     = *(const float4*)(&Xs[kk][ty * 8]);
            *(float4*)(a + 4) = *(const float4*)(&Xs[kk][ty * 8 + 4]);
            *(float4*)(b)     = *(const float4*)(&Wt[kk][tx * 8]);
            *(float4*)(b + 4) = *(const float4*)(&Wt[kk][tx * 8 + 4]);
#pragma unroll
            for (int i = 0; i < 8; ++i)
#pragma unroll
                for (int j = 0; j < 8; ++j) acc[i][j] = fmaf(a[i], b[j], acc[i][j]);
        }
        __syncthreads();
    }
#pragma unroll
    for (int i = 0; i < 8; ++i) {
        int row = row0 + ty * 8 + i;
        if (row >= n) continue;
#pragma unroll
        for (int j4 = 0; j4 < 2; ++j4) {
            int c = tx * 8 + j4 * 4;
            float4 r;
            r.x = acc[i][j4 * 4 + 0] + bias[c + 0];
            r.y = acc[i][j4 * 4 + 1] + bias[c + 1];
            r.z = acc[i][j4 * 4 + 2] + bias[c + 2];
            r.w = acc[i][j4 * 4 + 3] + bias[c + 3];
            *(float4*)(out + (size_t)row * 128 + c) = r;
        }
    }
}

// ---------------------------------------------------------------------------
// Per-target edge attention with online softmax. One wave per target node.
// h2 (pre-filled with x@Ws + bs) gets += softmax-weighted sum of v[src].
// 1-deep software pipeline on the k/v gather to hide L3 latency.
// ---------------------------------------------------------------------------
__global__ __launch_bounds__(256) void attn_kernel(
    const float* __restrict__ q, const float* __restrict__ k, const float* __restrict__ v,
    const int* __restrict__ rowptr, const int* __restrict__ esrc,
    float* __restrict__ h2, int n) {
    int wid = (blockIdx.x * blockDim.x + threadIdx.x) >> 6;
    int lane = threadIdx.x & 63;
    if (wid >= n) return;
    int f0 = lane * 2;
    float2 qv = *(const float2*)(q + (size_t)wid * 128 + f0);
    const float scale = 0.08838834764831845f;  // 1/sqrt(128)
    int beg = rowptr[wid], end = rowptr[wid + 1];
    if (beg == end) return;  // no in-edges: h2 stays = skip term (matches ref)
    float m = -3.402823466e38f, ssum = 0.f, acc0 = 0.f, acc1 = 0.f;
    int s0 = esrc[beg];
    float2 kvN = *(const float2*)(k + (size_t)s0 * 128 + f0);
    float2 vvN = *(const float2*)(v + (size_t)s0 * 128 + f0);
    for (int j = beg; j < end; ++j) {
        float2 kv = kvN, vv = vvN;
        if (j + 1 < end) {
            int s = esrc[j + 1];
            kvN = *(const float2*)(k + (size_t)s * 128 + f0);
            vvN = *(const float2*)(v + (size_t)s * 128 + f0);
        }
        float d = qv.x * kv.x + qv.y * kv.y;
#pragma unroll
        for (int off = 32; off; off >>= 1) d += __shfl_xor(d, off);
        d *= scale;
        if (d > m) {   // uniform across wave (d is wave-reduced)
            float r = __expf(m - d);  // first iter: exp(-huge) = 0
            ssum *= r; acc0 *= r; acc1 *= r; m = d;
        }
        float w = __expf(d - m);
        ssum += w;
        acc0 += w * vv.x;
        acc1 += w * vv.y;
    }
    float inv = 1.f / ssum;
    float2* o = (float2*)(h2 + (size_t)wid * 128 + f0);
    float2 cur = *o;
    cur.x += acc0 * inv;
    cur.y += acc1 * inv;
    *o = cur;
}

// ---------------------------------------------------------------------------
// BatchNorm (training stats). Apply+ReLU is fused into consumers.
// ---------------------------------------------------------------------------
__global__ __launch_bounds__(256) void bn_stats(const float* __restrict__ h2,
                                                float* __restrict__ psum,
                                                float* __restrict__ psq, int n) {
    int f = threadIdx.x & 127;
    int rp = threadIdx.x >> 7;  // 0..1
    float s = 0.f, s2 = 0.f;
    for (int r = blockIdx.x * 2 + rp; r < n; r += gridDim.x * 2) {
        float x = h2[(size_t)r * 128 + f];
        s += x;
        s2 += x * x;
    }
    __shared__ float sm[256], sm2[256];
    sm[threadIdx.x] = s;
    sm2[threadIdx.x] = s2;
    __syncthreads();
    if (rp == 0) {
        psum[blockIdx.x * 128 + f] = sm[f] + sm[128 + f];
        psq[blockIdx.x * 128 + f] = sm2[f] + sm2[128 + f];
    }
}

// 512 threads: 4 partial-slices per feature, LDS reduce. Kills the serial
// 256-iteration loop that dominated round-0's profile.
__global__ __launch_bounds__(512) void bn_finalize(const float* __restrict__ psum,
                                                   const float* __restrict__ psq,
                                                   const float* __restrict__ g,
                                                   const float* __restrict__ b,
                                                   float* __restrict__ scale,
                                                   float* __restrict__ shift, int n) {
    int f = threadIdx.x & 127, part = threadIdx.x >> 7;  // part 0..3
    float s = 0.f, s2 = 0.f;
#pragma unroll 4
    for (int i = part; i < 256; i += 4) {
        s += psum[i * 128 + f];
        s2 += psq[i * 128 + f];
    }
    __shared__ float sa[512], sb[512];
    sa[threadIdx.x] = s;
    sb[threadIdx.x] = s2;
    __syncthreads();
    if (part == 0) {
        s = sa[f] + sa[128 + f] + sa[256 + f] + sa[384 + f];
        s2 = sb[f] + sb[128 + f] + sb[256 + f] + sb[384 + f];
        float inv_n = 1.f / (float)n;
        float mu = s * inv_n;
        float var = s2 * inv_n - mu * mu;
        float sc = g[f] * rsqrtf(var + 1e-5f);
        scale[f] = sc;
        shift[f] = b[f] - mu * sc;
    }
}

// ---------------------------------------------------------------------------
// Pool (batch sorted -> contiguous row range per graph) with fused BN+ReLU,
// then classifier head.
// ---------------------------------------------------------------------------
__global__ __launch_bounds__(256) void pool_kernel(const float* __restrict__ h,
                                                   const float* __restrict__ bnsc,
                                                   const float* __restrict__ bnsh,
                                                   const int* __restrict__ batch,
                                                   float* __restrict__ pooled, int n) {
    int g = blockIdx.x;
    int lo = 0, hi = n;
    while (lo < hi) { int mid = (lo + hi) >> 1; if (batch[mid] < g) lo = mid + 1; else hi = mid; }
    int start = lo;
    lo = start; hi = n;
    while (lo < hi) { int mid = (lo + hi) >> 1; if (batch[mid] < g + 1) lo = mid + 1; else hi = mid; }
    int end = lo;
    int f = threadIdx.x & 127, rp = threadIdx.x >> 7;
    float sc = bnsc[f], sh = bnsh[f];
    float s = 0.f;
    for (int r = start + rp; r < end; r += 2)
        s += fmaxf(0.f, fmaf(h[(size_t)r * 128 + f], sc, sh));
    __shared__ float sm[256];
    sm[threadIdx.x] = s;
    __syncthreads();
    if (rp == 0) {
        float tot = sm[f] + sm[128 + f];
        float cnt = (float)(end - start);
        pooled[g * 128 + f] = tot / fmaxf(cnt, 1.f);
    }
}

__global__ void head_kernel(const float* __restrict__ pooled, const float* __restrict__ W,
                            const float* __restrict__ bias, float* __restrict__ out) {
    int g = blockIdx.x;
    int lane = threadIdx.x;  // 64
    float p0 = pooled[g * 128 + lane];
    float p1 = pooled[g * 128 + 64 + lane];
#pragma unroll
    for (int c = 0; c < C_CLASSES; ++c) {
        float d = p0 * W[lane * C_CLASSES + c] + p1 * W[(64 + lane) * C_CLASSES + c];
#pragma unroll
        for (int off = 32; off; off >>= 1) d += __shfl_xor(d, off);
        if (lane == 0) out[g * C_CLASSES + c] = d + bias[c];
    }
}

// ---------------------------------------------------------------------------
extern "C" void kernel_launch(void* const* d_in, const int* in_sizes, int n_in,
                              void* d_out, int out_size, void* d_ws, size_t ws_size,
                              hipStream_t stream) {
    const int N = in_sizes[0] / IN_DIM;       // 100000
    const int E = in_sizes[1] / 2;            // 600000

    const float* x     = (const float*)d_in[0];
    const int* ei      = (const int*)d_in[1];
    const int* src     = ei;
    const int* dst     = ei + E;
    const int* batch   = (const int*)d_in[2];
    const float* Wq1 = (const float*)d_in[3],  *bq1 = (const float*)d_in[4];
    const float* Wk1 = (const float*)d_in[5],  *bk1 = (const float*)d_in[6];
    const float* Wv1 = (const float*)d_in[7],  *bv1 = (const float*)d_in[8];
    const float* Ws1 = (const float*)d_in[9],  *bs1 = (const float*)d_in[10];
    const float* bn1g = (const float*)d_in[11], *bn1b = (const float*)d_in[12];
    const float* Wq = (const float*)d_in[13], *bq = (const float*)d_in[14];
    const float* Wk = (const float*)d_in[15], *bk = (const float*)d_in[16];
    const float* Wv = (const float*)d_in[17], *bv = (const float*)d_in[18];
    const float* Ws = (const float*)d_in[19], *bs = (const float*)d_in[20];
    const float* bng = (const float*)d_in[21], *bnb = (const float*)d_in[22];
    const float* linW = (const float*)d_in[23], *linb = (const float*)d_in[24];
    float* out = (float*)d_out;

    // workspace layout
    char* w = (char*)d_ws;
    auto alloc = [&](size_t bytes) -> char* {
        char* p = w;
        w += (bytes + 255) & ~(size_t)255;
        return p;
    };
    const size_t NH = (size_t)N * H_DIM;
    float* q    = (float*)alloc(NH * 4);
    float* kbuf = (float*)alloc(NH * 4);
    float* vbuf = (float*)alloc(NH * 4);
    float* bufA = (float*)alloc(NH * 4);   // conv output ping
    float* bufB = (float*)alloc(NH * 4);   // conv output pong
    float* psum = (float*)alloc(256 * 128 * 4);
    float* psq  = (float*)alloc(256 * 128 * 4);
    float* bnsc = (float*)alloc(128 * 4);
    float* bnsh = (float*)alloc(128 * 4);
    float* pooled = (float*)alloc(G_GRAPHS * H_DIM * 4);
    int* deg    = (int*)alloc((size_t)N * 4);
    int* rowptr = (int*)alloc((size_t)(N + 1) * 4);
    int* wpos   = (int*)alloc((size_t)N * 4);
    int* esrc   = (int*)alloc((size_t)E * 4);
    int* bsum   = (int*)alloc(((size_t)(N + 255) / 256) * 4);

    const int nblk = (N + 255) / 256;        // 391
    const int egrid = (E + 255) / 256;

    // ---- CSR build (per call; ws is re-poisoned between launches)
    hipMemsetAsync(deg, 0, (size_t)N * 4, stream);
    count_deg<<<egrid, 256, 0, stream>>>(dst, deg, E);
    scan1<<<nblk, 256, 0, stream>>>(deg, rowptr, bsum, N);
    scan2<<<1, 512, 0, stream>>>(bsum, nblk);
    scan3<<<nblk, 256, 0, stream>>>(rowptr, wpos, bsum, deg, N);
    scatter_edges<<<egrid, 256, 0, stream>>>(src, dst, wpos, esrc, E);

    const int gx = (N + 127) / 128;          // 782
    const int attn_blocks = (N + 3) / 4;     // 4 waves/block

    // ---- layer 1 (IN=64, raw x input, no fused BN)
    gemm_qkvs<IN_DIM, false><<<dim3(gx, 4), 256, 0, stream>>>(
        x, N, nullptr, nullptr, Wq1, bq1, Wk1, bk1, Wv1, bv1, Ws1, bs1,
        q, kbuf, vbuf, bufA);
    attn_kernel<<<attn_blocks, 256, 0, stream>>>(q, kbuf, vbuf, rowptr, esrc, bufA, N);
    bn_stats<<<256, 256, 0, stream>>>(bufA, psum, psq, N);
    bn_finalize<<<1, 512, 0, stream>>>(psum, psq, bn1g, bn1b, bnsc, bnsh, N);

    // ---- layers 2..4 (H=128); BN+ReLU of previous layer fused into X staging
    const float* cur = bufA;
    float* nxt = bufB;
    for (int i = 0; i < L_LAYERS; ++i) {
        const size_t wo = (size_t)i * H_DIM * H_DIM;
        const size_t bo = (size_t)i * H_DIM;
        gemm_qkvs<H_DIM, true><<<dim3(gx, 4), 256, 0, stream>>>(
            cur, N, bnsc, bnsh, Wq + wo, bq + bo, Wk + wo, bk + bo,
            Wv + wo, bv + bo, Ws + wo, bs + bo, q, kbuf, vbuf, nxt);
        attn_kernel<<<attn_blocks, 256, 0, stream>>>(q, kbuf, vbuf, rowptr, esrc, nxt, N);
        bn_stats<<<256, 256, 0, stream>>>(nxt, psum, psq, N);
        bn_finalize<<<1, 512, 0, stream>>>(psum, psq, bng + bo, bnb + bo, bnsc, bnsh, N);
        // ping-pong
        const float* tmp = cur; cur = nxt; nxt = (float*)tmp;
    }

    // ---- pool (fused BN+ReLU of last layer) + head
    pool_kernel<<<G_GRAPHS, 256, 0, stream>>>(cur, bnsc, bnsh, batch, pooled, N);
    head_kernel<<<G_GRAPHS, 64, 0, stream>>>(pooled, linW, linb, out);
}

// Round 3
// 1344.685 us; speedup vs baseline: 4.3356x; 4.0278x over previous
//
#include <hip/hip_runtime.h>
#include <hip/hip_bf16.h>

// Problem constants
#define IN_DIM 64
#define H_DIM 128
#define L_LAYERS 3
#define G_GRAPHS 256
#define C_CLASSES 10

typedef short bf16x8 __attribute__((ext_vector_type(8)));
typedef float f32x4 __attribute__((ext_vector_type(4)));

// Truncation split: x = hi + lo + eps, |eps| <~ 2^-15 |x|.
__device__ inline void bsplit(float x, unsigned short& h, unsigned short& l) {
    unsigned u = __float_as_uint(x);
    unsigned hb = u & 0xFFFF0000u;
    h = (unsigned short)(u >> 16);
    float r = x - __uint_as_float(hb);
    unsigned v = __float_as_uint(r);
    v += 0x7FFFu + ((v >> 16) & 1u);   // RNE to bf16
    l = (unsigned short)(v >> 16);
}

// ---------------------------------------------------------------------------
// CSR build
// ---------------------------------------------------------------------------
__global__ void count_deg(const int* __restrict__ dst, int* __restrict__ deg, int e) {
    int i = blockIdx.x * blockDim.x + threadIdx.x;
    if (i < e) atomicAdd(&deg[dst[i]], 1);
}

__global__ __launch_bounds__(256) void scan1(const int* __restrict__ deg,
                                             int* __restrict__ rowptr,
                                             int* __restrict__ bsum, int n) {
    int i = blockIdx.x * 256 + threadIdx.x;
    int v = (i < n) ? deg[i] : 0;
    __shared__ int sm[256];
    sm[threadIdx.x] = v;
    __syncthreads();
    for (int off = 1; off < 256; off <<= 1) {
        int x = (threadIdx.x >= off) ? sm[threadIdx.x - off] : 0;
        __syncthreads();
        sm[threadIdx.x] += x;
        __syncthreads();
    }
    if (i < n) rowptr[i + 1] = sm[threadIdx.x];
    if (threadIdx.x == 255) bsum[blockIdx.x] = sm[255];
}

__global__ __launch_bounds__(512) void scan2(int* __restrict__ bsum, int nblk) {
    __shared__ int sm[512];
    int t = threadIdx.x;
    int v = (t < nblk) ? bsum[t] : 0;
    sm[t] = v;
    __syncthreads();
    for (int off = 1; off < 512; off <<= 1) {
        int x = (t >= off) ? sm[t - off] : 0;
        __syncthreads();
        sm[t] += x;
        __syncthreads();
    }
    if (t < nblk) bsum[t] = sm[t] - v;  // exclusive
}

__global__ void scan3(int* __restrict__ rowptr, int* __restrict__ wpos,
                      const int* __restrict__ bsum, const int* __restrict__ deg, int n) {
    int i = blockIdx.x * 256 + threadIdx.x;
    if (i < n) {
        int incl = rowptr[i + 1] + bsum[i >> 8];
        rowptr[i + 1] = incl;
        wpos[i] = incl - deg[i];
    }
    if (i == 0) rowptr[0] = 0;
}

__global__ void scatter_edges(const int* __restrict__ src, const int* __restrict__ dst,
                              int* __restrict__ wpos, int* __restrict__ esrc, int e) {
    int i = blockIdx.x * blockDim.x + threadIdx.x;
    if (i < e) {
        int pos = atomicAdd(&wpos[dst[i]], 1);
        esrc[pos] = src[i];
    }
}

// ---------------------------------------------------------------------------
// prep_x: fp32 activations -> fragment-major hi/lo bf16, optional fused BN+ReLU.
// Fragment layout (elems): frag f = (row>>4)*(K>>5) + (k>>5); within frag:
// lane = ((k>>3)&3)*16 + (row&15); elem j = k&7. Stored as [f][hi:512 | lo:512].
// ---------------------------------------------------------------------------
template <int K, bool BN>
__global__ __launch_bounds__(256) void prep_x(const float* __restrict__ X, int nrows,
                                              int rows_pad,
                                              const float* __restrict__ bnsc,
                                              const float* __restrict__ bnsh,
                                              unsigned short* __restrict__ XF) {
    const int GPR = K / 8;  // 8-elem groups per row
    int e8 = blockIdx.x * 256 + threadIdx.x;
    int row = e8 / GPR;
    int k0 = (e8 - row * GPR) * 8;
    if (row >= rows_pad) return;
    float v[8];
    if (row < nrows) {
        float4 a = *(const float4*)(X + (size_t)row * K + k0);
        float4 b = *(const float4*)(X + (size_t)row * K + k0 + 4);
        v[0] = a.x; v[1] = a.y; v[2] = a.z; v[3] = a.w;
        v[4] = b.x; v[5] = b.y; v[6] = b.z; v[7] = b.w;
        if (BN) {
            float4 s0 = *(const float4*)(bnsc + k0);
            float4 s1 = *(const float4*)(bnsc + k0 + 4);
            float4 h0 = *(const float4*)(bnsh + k0);
            float4 h1 = *(const float4*)(bnsh + k0 + 4);
            v[0] = fmaxf(0.f, fmaf(v[0], s0.x, h0.x));
            v[1] = fmaxf(0.f, fmaf(v[1], s0.y, h0.y));
            v[2] = fmaxf(0.f, fmaf(v[2], s0.z, h0.z));
            v[3] = fmaxf(0.f, fmaf(v[3], s0.w, h0.w));
            v[4] = fmaxf(0.f, fmaf(v[4], s1.x, h1.x));
            v[5] = fmaxf(0.f, fmaf(v[5], s1.y, h1.y));
            v[6] = fmaxf(0.f, fmaf(v[6], s1.z, h1.z));
            v[7] = fmaxf(0.f, fmaf(v[7], s1.w, h1.w));
        }
    } else {
#pragma unroll
        for (int j = 0; j < 8; ++j) v[j] = 0.f;
    }
    unsigned short h[8], l[8];
#pragma unroll
    for (int j = 0; j < 8; ++j) bsplit(v[j], h[j], l[j]);
    size_t f = (size_t)(row >> 4) * (K >> 5) + (k0 >> 5);
    int lane = ((k0 >> 3) & 3) * 16 + (row & 15);
    unsigned short* p = XF + f * 1024 + lane * 8;
    uint4 hv, lv;
    hv.x = h[0] | (h[1] << 16); hv.y = h[2] | (h[3] << 16);
    hv.z = h[4] | (h[5] << 16); hv.w = h[6] | (h[7] << 16);
    lv.x = l[0] | (l[1] << 16); lv.y = l[2] | (l[3] << 16);
    lv.z = l[4] | (l[5] << 16); lv.w = l[6] | (l[7] << 16);
    *(uint4*)p = hv;
    *(uint4*)(p + 512) = lv;
}

// ---------------------------------------------------------------------------
// prep_w: 4 fp32 weights [K][128] -> fragment-major hi/lo bf16 (B-operand).
// frag f = (col>>4)*(K>>5) + (k>>5); lane = ((k>>3)&3)*16 + (col&15); j = k&7.
// ---------------------------------------------------------------------------
template <int K>
__global__ __launch_bounds__(256) void prep_w(const float* __restrict__ W0,
                                              const float* __restrict__ W1,
                                              const float* __restrict__ W2,
                                              const float* __restrict__ W3,
                                              unsigned short* __restrict__ WF) {
    const float* W;
    switch (blockIdx.y) {
        case 0:  W = W0; break;
        case 1:  W = W1; break;
        case 2:  W = W2; break;
        default: W = W3; break;
    }
    const int GPC = K / 8;  // 8-elem k-groups per column
    int e8 = blockIdx.x * 256 + threadIdx.x;
    if (e8 >= K * 16) return;  // K*128/8
    int col = e8 / GPC;
    int k0 = (e8 - col * GPC) * 8;
    float v[8];
#pragma unroll
    for (int j = 0; j < 8; ++j) v[j] = W[(size_t)(k0 + j) * 128 + col];
    unsigned short h[8], l[8];
#pragma unroll
    for (int j = 0; j < 8; ++j) bsplit(v[j], h[j], l[j]);
    size_t f = (size_t)(col >> 4) * (K >> 5) + (k0 >> 5);
    int lane = ((k0 >> 3) & 3) * 16 + (col & 15);
    const size_t wstride = (size_t)8 * (K >> 5) * 1024;
    unsigned short* p = WF + blockIdx.y * wstride + f * 1024 + lane * 8;
    uint4 hv, lv;
    hv.x = h[0] | (h[1] << 16); hv.y = h[2] | (h[3] << 16);
    hv.z = h[4] | (h[5] << 16); hv.w = h[6] | (h[7] << 16);
    lv.x = l[0] | (l[1] << 16); lv.y = l[2] | (l[3] << 16);
    lv.z = l[4] | (l[5] << 16); lv.w = l[6] | (l[7] << 16);
    *(uint4*)p = hv;
    *(uint4*)(p + 512) = lv;
}

// ---------------------------------------------------------------------------
// LDS-free MFMA GEMM: each wave computes a 32-row x 128-col output strip.
// A-frags (hi/lo) loaded lane-linear from XF; B-frags from WF (L2-hot, 64KB).
// 4-term split product: hh + hl + lh + ll -> ~fp32 accuracy, bf16 MFMA rate.
// ---------------------------------------------------------------------------
template <int K>
__global__ __launch_bounds__(256) void gemm_mfma(
    const unsigned short* __restrict__ XF, const unsigned short* __restrict__ WF,
    int n, int strips,
    const float* __restrict__ b0, const float* __restrict__ b1,
    const float* __restrict__ b2, const float* __restrict__ b3,
    float* __restrict__ o0, float* __restrict__ o1,
    float* __restrict__ o2, float* __restrict__ o3) {
    const float* bias; float* out;
    switch (blockIdx.y) {
        case 0:  bias = b0; out = o0; break;
        case 1:  bias = b1; out = o1; break;
        case 2:  bias = b2; out = o2; break;
        default: bias = b3; out = o3; break;
    }
    constexpr int KB = K >> 5;
    const unsigned short* WFy = WF + (size_t)blockIdx.y * (8 * KB * 1024);
    int wid = (blockIdx.x * 256 + threadIdx.x) >> 6;  // strip id
    int l = threadIdx.x & 63;
    if (wid >= strips) return;

    // Load all A fragments for this strip: 2 mfrag x KB kblk x {hi,lo}
    bf16x8 A[2][KB][2];
#pragma unroll
    for (int mf = 0; mf < 2; ++mf)
#pragma unroll
        for (int kb = 0; kb < KB; ++kb) {
            const unsigned short* p =
                XF + ((size_t)(wid * 2 + mf) * KB + kb) * 1024 + l * 8;
            A[mf][kb][0] = *(const bf16x8*)p;
            A[mf][kb][1] = *(const bf16x8*)(p + 512);
        }

#pragma unroll
    for (int nf = 0; nf < 8; ++nf) {
        bf16x8 B[KB][2];
#pragma unroll
        for (int kb = 0; kb < KB; ++kb) {
            const unsigned short* p = WFy + ((size_t)(nf * KB + kb)) * 1024 + l * 8;
            B[kb][0] = *(const bf16x8*)p;
            B[kb][1] = *(const bf16x8*)(p + 512);
        }
        f32x4 acc[2];
        acc[0] = (f32x4){0.f, 0.f, 0.f, 0.f};
        acc[1] = (f32x4){0.f, 0.f, 0.f, 0.f};
#pragma unroll
        for (int kb = 0; kb < KB; ++kb) {
#pragma unroll
            for (int mf = 0; mf < 2; ++mf) {
                acc[mf] = __builtin_amdgcn_mfma_f32_16x16x32_bf16(
                    A[mf][kb][0], B[kb][0], acc[mf], 0, 0, 0);
                acc[mf] = __builtin_amdgcn_mfma_f32_16x16x32_bf16(
                    A[mf][kb][0], B[kb][1], acc[mf], 0, 0, 0);
                acc[mf] = __builtin_amdgcn_mfma_f32_16x16x32_bf16(
                    A[mf][kb][1], B[kb][0], acc[mf], 0, 0, 0);
                acc[mf] = __builtin_amdgcn_mfma_f32_16x16x32_bf16(
                    A[mf][kb][1], B[kb][1], acc[mf], 0, 0, 0);
            }
        }
        int col = nf * 16 + (l & 15);
        float bb = bias[col];
        int rbase = wid * 32 + ((l >> 4) << 2);
#pragma unroll
        for (int mf = 0; mf < 2; ++mf)
#pragma unroll
            for (int r = 0; r < 4; ++r) {
                int row = rbase + mf * 16 + r;
                if (row < n) out[(size_t)row * 128 + col] = acc[mf][r] + bb;
            }
    }
}

// ---------------------------------------------------------------------------
// Per-target edge attention with online softmax (1-deep gather pipeline).
// ---------------------------------------------------------------------------
__global__ __launch_bounds__(256) void attn_kernel(
    const float* __restrict__ q, const float* __restrict__ k, const float* __restrict__ v,
    const int* __restrict__ rowptr, const int* __restrict__ esrc,
    float* __restrict__ h2, int n) {
    int wid = (blockIdx.x * blockDim.x + threadIdx.x) >> 6;
    int lane = threadIdx.x & 63;
    if (wid >= n) return;
    int f0 = lane * 2;
    float2 qv = *(const float2*)(q + (size_t)wid * 128 + f0);
    const float scale = 0.08838834764831845f;  // 1/sqrt(128)
    int beg = rowptr[wid], end = rowptr[wid + 1];
    if (beg == end) return;
    float m = -3.402823466e38f, ssum = 0.f, acc0 = 0.f, acc1 = 0.f;
    int s0 = esrc[beg];
    float2 kvN = *(const float2*)(k + (size_t)s0 * 128 + f0);
    float2 vvN = *(const float2*)(v + (size_t)s0 * 128 + f0);
    for (int j = beg; j < end; ++j) {
        float2 kv = kvN, vv = vvN;
        if (j + 1 < end) {
            int s = esrc[j + 1];
            kvN = *(const float2*)(k + (size_t)s * 128 + f0);
            vvN = *(const float2*)(v + (size_t)s * 128 + f0);
        }
        float d = qv.x * kv.x + qv.y * kv.y;
#pragma unroll
        for (int off = 32; off; off >>= 1) d += __shfl_xor(d, off);
        d *= scale;
        if (d > m) {
            float r = __expf(m - d);
            ssum *= r; acc0 *= r; acc1 *= r; m = d;
        }
        float w = __expf(d - m);
        ssum += w;
        acc0 += w * vv.x;
        acc1 += w * vv.y;
    }
    float inv = 1.f / ssum;
    float2* o = (float2*)(h2 + (size_t)wid * 128 + f0);
    float2 cur = *o;
    cur.x += acc0 * inv;
    cur.y += acc1 * inv;
    *o = cur;
}

// ---------------------------------------------------------------------------
// BatchNorm stats (apply is fused into prep_x / pool)
// ---------------------------------------------------------------------------
__global__ __launch_bounds__(256) void bn_stats(const float* __restrict__ h2,
                                                float* __restrict__ psum,
                                                float* __restrict__ psq, int n) {
    int f = threadIdx.x & 127;
    int rp = threadIdx.x >> 7;
    float s = 0.f, s2 = 0.f;
    for (int r = blockIdx.x * 2 + rp; r < n; r += gridDim.x * 2) {
        float x = h2[(size_t)r * 128 + f];
        s += x;
        s2 += x * x;
    }
    __shared__ float sm[256], sm2[256];
    sm[threadIdx.x] = s;
    sm2[threadIdx.x] = s2;
    __syncthreads();
    if (rp == 0) {
        psum[blockIdx.x * 128 + f] = sm[f] + sm[128 + f];
        psq[blockIdx.x * 128 + f] = sm2[f] + sm2[128 + f];
    }
}

__global__ __launch_bounds__(512) void bn_finalize(const float* __restrict__ psum,
                                                   const float* __restrict__ psq,
                                                   const float* __restrict__ g,
                                                   const float* __restrict__ b,
                                                   float* __restrict__ scale,
                                                   float* __restrict__ shift, int n) {
    int f = threadIdx.x & 127, part = threadIdx.x >> 7;
    float s = 0.f, s2 = 0.f;
#pragma unroll 4
    for (int i = part; i < 256; i += 4) {
        s += psum[i * 128 + f];
        s2 += psq[i * 128 + f];
    }
    __shared__ float sa[512], sb[512];
    sa[threadIdx.x] = s;
    sb[threadIdx.x] = s2;
    __syncthreads();
    if (part == 0) {
        s = sa[f] + sa[128 + f] + sa[256 + f] + sa[384 + f];
        s2 = sb[f] + sb[128 + f] + sb[256 + f] + sb[384 + f];
        float inv_n = 1.f / (float)n;
        float mu = s * inv_n;
        float var = s2 * inv_n - mu * mu;
        float sc = g[f] * rsqrtf(var + 1e-5f);
        scale[f] = sc;
        shift[f] = b[f] - mu * sc;
    }
}

// ---------------------------------------------------------------------------
// Pool (fused BN+ReLU of last layer) + head
// ---------------------------------------------------------------------------
__global__ __launch_bounds__(256) void pool_kernel(const float* __restrict__ h,
                                                   const float* __restrict__ bnsc,
                                                   const float* __restrict__ bnsh,
                                                   const int* __restrict__ batch,
                                                   float* __restrict__ pooled, int n) {
    int g = blockIdx.x;
    int lo = 0, hi = n;
    while (lo < hi) { int mid = (lo + hi) >> 1; if (batch[mid] < g) lo = mid + 1; else hi = mid; }
    int start = lo;
    lo = start; hi = n;
    while (lo < hi) { int mid = (lo + hi) >> 1; if (batch[mid] < g + 1) lo = mid + 1; else hi = mid; }
    int end = lo;
    int f = threadIdx.x & 127, rp = threadIdx.x >> 7;
    float sc = bnsc[f], sh = bnsh[f];
    float s = 0.f;
    for (int r = start + rp; r < end; r += 2)
        s += fmaxf(0.f, fmaf(h[(size_t)r * 128 + f], sc, sh));
    __shared__ float sm[256];
    sm[threadIdx.x] = s;
    __syncthreads();
    if (rp == 0) {
        float tot = sm[f] + sm[128 + f];
        float cnt = (float)(end - start);
        pooled[g * 128 + f] = tot / fmaxf(cnt, 1.f);
    }
}

__global__ void head_kernel(const float* __restrict__ pooled, const float* __restrict__ W,
                            const float* __restrict__ bias, float* __restrict__ out) {
    int g = blockIdx.x;
    int lane = threadIdx.x;  // 64
    float p0 = pooled[g * 128 + lane];
    float p1 = pooled[g * 128 + 64 + lane];
#pragma unroll
    for (int c = 0; c < C_CLASSES; ++c) {
        float d = p0 * W[lane * C_CLASSES + c] + p1 * W[(64 + lane) * C_CLASSES + c];
#pragma unroll
        for (int off = 32; off; off >>= 1) d += __shfl_xor(d, off);
        if (lane == 0) out[g * C_CLASSES + c] = d + bias[c];
    }
}

// ---------------------------------------------------------------------------
extern "C" void kernel_launch(void* const* d_in, const int* in_sizes, int n_in,
                              void* d_out, int out_size, void* d_ws, size_t ws_size,
                              hipStream_t stream) {
    const int N = in_sizes[0] / IN_DIM;       // 100000
    const int E = in_sizes[1] / 2;            // 600000

    const float* x     = (const float*)d_in[0];
    const int* ei      = (const int*)d_in[1];
    const int* src     = ei;
    const int* dst     = ei + E;
    const int* batch   = (const int*)d_in[2];
    const float* Wq1 = (const float*)d_in[3],  *bq1 = (const float*)d_in[4];
    const float* Wk1 = (const float*)d_in[5],  *bk1 = (const float*)d_in[6];
    const float* Wv1 = (const float*)d_in[7],  *bv1 = (const float*)d_in[8];
    const float* Ws1 = (const float*)d_in[9],  *bs1 = (const float*)d_in[10];
    const float* bn1g = (const float*)d_in[11], *bn1b = (const float*)d_in[12];
    const float* Wq = (const float*)d_in[13], *bq = (const float*)d_in[14];
    const float* Wk = (const float*)d_in[15], *bk = (const float*)d_in[16];
    const float* Wv = (const float*)d_in[17], *bv = (const float*)d_in[18];
    const float* Ws = (const float*)d_in[19], *bs = (const float*)d_in[20];
    const float* bng = (const float*)d_in[21], *bnb = (const float*)d_in[22];
    const float* linW = (const float*)d_in[23], *linb = (const float*)d_in[24];
    float* out = (float*)d_out;

    const int RB = (N + 127) / 128;           // 782 row-blocks
    const int rows_pad = RB * 128;            // 100096
    const int strips = rows_pad / 32;         // 3128

    // workspace layout
    char* w = (char*)d_ws;
    auto alloc = [&](size_t bytes) -> char* {
        char* p = w;
        w += (bytes + 255) & ~(size_t)255;
        return p;
    };
    const size_t NH = (size_t)N * H_DIM;
    float* q    = (float*)alloc(NH * 4);
    float* kbuf = (float*)alloc(NH * 4);
    float* vbuf = (float*)alloc(NH * 4);
    float* conv = (float*)alloc(NH * 4);   // conv output (skip + attn agg)
    unsigned short* XF = (unsigned short*)alloc((size_t)rows_pad * H_DIM * 2 * 2);  // 51.25MB
    unsigned short* WF = (unsigned short*)alloc((size_t)4 * H_DIM * H_DIM * 2 * 2); // 256KB
    float* psum = (float*)alloc(256 * 128 * 4);
    float* psq  = (float*)alloc(256 * 128 * 4);
    float* bnsc = (float*)alloc(128 * 4);
    float* bnsh = (float*)alloc(128 * 4);
    float* pooled = (float*)alloc(G_GRAPHS * H_DIM * 4);
    int* deg    = (int*)alloc((size_t)N * 4);
    int* rowptr = (int*)alloc((size_t)(N + 1) * 4);
    int* wpos   = (int*)alloc((size_t)N * 4);
    int* esrc   = (int*)alloc((size_t)E * 4);
    int* bsum   = (int*)alloc(((size_t)(N + 255) / 256) * 4);

    const int nblk = (N + 255) / 256;
    const int egrid = (E + 255) / 256;

    // ---- CSR build
    hipMemsetAsync(deg, 0, (size_t)N * 4, stream);
    count_deg<<<egrid, 256, 0, stream>>>(dst, deg, E);
    scan1<<<nblk, 256, 0, stream>>>(deg, rowptr, bsum, N);
    scan2<<<1, 512, 0, stream>>>(bsum, nblk);
    scan3<<<nblk, 256, 0, stream>>>(rowptr, wpos, bsum, deg, N);
    scatter_edges<<<egrid, 256, 0, stream>>>(src, dst, wpos, esrc, E);

    const int attn_blocks = (N + 3) / 4;

    // ---- layer 1 (K=64, raw input, no BN)
    {
        const int px_grid = rows_pad * IN_DIM / 8 / 256;      // 3128
        prep_x<IN_DIM, false><<<px_grid, 256, 0, stream>>>(x, N, rows_pad, nullptr, nullptr, XF);
        prep_w<IN_DIM><<<dim3((IN_DIM * 16 + 255) / 256, 4), 256, 0, stream>>>(Wq1, Wk1, Wv1, Ws1, WF);
        gemm_mfma<IN_DIM><<<dim3(strips / 4, 4), 256, 0, stream>>>(
            XF, WF, N, strips, bq1, bk1, bv1, bs1, q, kbuf, vbuf, conv);
        attn_kernel<<<attn_blocks, 256, 0, stream>>>(q, kbuf, vbuf, rowptr, esrc, conv, N);
        bn_stats<<<256, 256, 0, stream>>>(conv, psum, psq, N);
        bn_finalize<<<1, 512, 0, stream>>>(psum, psq, bn1g, bn1b, bnsc, bnsh, N);
    }

    // ---- layers 2..4 (K=128, BN+ReLU fused into prep_x)
    for (int i = 0; i < L_LAYERS; ++i) {
        const size_t wo = (size_t)i * H_DIM * H_DIM;
        const size_t bo = (size_t)i * H_DIM;
        const int px_grid = rows_pad * H_DIM / 8 / 256;       // 6256
        prep_x<H_DIM, true><<<px_grid, 256, 0, stream>>>(conv, N, rows_pad, bnsc, bnsh, XF);
        prep_w<H_DIM><<<dim3((H_DIM * 16 + 255) / 256, 4), 256, 0, stream>>>(
            Wq + wo, Wk + wo, Wv + wo, Ws + wo, WF);
        gemm_mfma<H_DIM><<<dim3(strips / 4, 4), 256, 0, stream>>>(
            XF, WF, N, strips, bq + bo, bk + bo, bv + bo, bs + bo, q, kbuf, vbuf, conv);
        attn_kernel<<<attn_blocks, 256, 0, stream>>>(q, kbuf, vbuf, rowptr, esrc, conv, N);
        bn_stats<<<256, 256, 0, stream>>>(conv, psum, psq, N);
        bn_finalize<<<1, 512, 0, stream>>>(psum, psq, bng + bo, bnb + bo, bnsc, bnsh, N);
    }

    // ---- pool (fused last BN+ReLU) + head
    pool_kernel<<<G_GRAPHS, 256, 0, stream>>>(conv, bnsc, bnsh, batch, pooled, N);
    head_kernel<<<G_GRAPHS, 64, 0, stream>>>(pooled, linW, linb, out);
}

// Round 4
// 1235.411 us; speedup vs baseline: 4.7191x; 1.0885x over previous
//
#include <hip/hip_runtime.h>
#include <hip/hip_bf16.h>

// Problem constants
#define IN_DIM 64
#define H_DIM 128
#define L_LAYERS 3
#define G_GRAPHS 256
#define C_CLASSES 10

typedef short bf16x8 __attribute__((ext_vector_type(8)));
typedef float f32x4 __attribute__((ext_vector_type(4)));

__device__ inline unsigned short bf16rne(float x) {
    unsigned v = __float_as_uint(x);
    v += 0x7FFFu + ((v >> 16) & 1u);
    return (unsigned short)(v >> 16);
}

// RNE split: x = hi + lo + eps, |lo| <= 2^-9 |x|, |eps| <~ 2^-17 |x|.
__device__ inline void bsplit(float x, unsigned short& h, unsigned short& l) {
    h = bf16rne(x);
    float hf = __uint_as_float((unsigned)h << 16);
    l = bf16rne(x - hf);
}

// ---------------------------------------------------------------------------
// CSR build (atomic-free scatter: count pass records per-edge rank)
// ---------------------------------------------------------------------------
__global__ void count_deg(const int* __restrict__ dst, int* __restrict__ deg,
                          int* __restrict__ erank, int e) {
    int i = blockIdx.x * blockDim.x + threadIdx.x;
    if (i < e) erank[i] = atomicAdd(&deg[dst[i]], 1);
}

__global__ __launch_bounds__(256) void scan1(const int* __restrict__ deg,
                                             int* __restrict__ rowptr,
                                             int* __restrict__ bsum, int n) {
    int i = blockIdx.x * 256 + threadIdx.x;
    int v = (i < n) ? deg[i] : 0;
    __shared__ int sm[256];
    sm[threadIdx.x] = v;
    __syncthreads();
    for (int off = 1; off < 256; off <<= 1) {
        int x = (threadIdx.x >= off) ? sm[threadIdx.x - off] : 0;
        __syncthreads();
        sm[threadIdx.x] += x;
        __syncthreads();
    }
    if (i < n) rowptr[i + 1] = sm[threadIdx.x];
    if (threadIdx.x == 255) bsum[blockIdx.x] = sm[255];
}

__global__ __launch_bounds__(512) void scan2(int* __restrict__ bsum, int nblk) {
    __shared__ int sm[512];
    int t = threadIdx.x;
    int v = (t < nblk) ? bsum[t] : 0;
    sm[t] = v;
    __syncthreads();
    for (int off = 1; off < 512; off <<= 1) {
        int x = (t >= off) ? sm[t - off] : 0;
        __syncthreads();
        sm[t] += x;
        __syncthreads();
    }
    if (t < nblk) bsum[t] = sm[t] - v;  // exclusive
}

__global__ void scan3(int* __restrict__ rowptr, const int* __restrict__ bsum, int n) {
    int i = blockIdx.x * 256 + threadIdx.x;
    if (i < n) rowptr[i + 1] += bsum[i >> 8];
    if (i == 0) rowptr[0] = 0;
}

__global__ void scatter_edges(const int* __restrict__ src, const int* __restrict__ dst,
                              const int* __restrict__ rowptr, const int* __restrict__ erank,
                              int* __restrict__ esrc, int e) {
    int i = blockIdx.x * blockDim.x + threadIdx.x;
    if (i < e) esrc[rowptr[dst[i]] + erank[i]] = src[i];
}

// ---------------------------------------------------------------------------
// prep_x: fp32 activations -> fragment-major hi/lo bf16, optional fused BN+ReLU.
// frag f = (row>>4)*(K>>5) + (k>>5); lane = ((k>>3)&3)*16 + (row&15); j = k&7.
// ---------------------------------------------------------------------------
template <int K, bool BN>
__global__ __launch_bounds__(256) void prep_x(const float* __restrict__ X, int nrows,
                                              int rows_pad,
                                              const float* __restrict__ bnsc,
                                              const float* __restrict__ bnsh,
                                              unsigned short* __restrict__ XF) {
    const int GPR = K / 8;
    int e8 = blockIdx.x * 256 + threadIdx.x;
    int row = e8 / GPR;
    int k0 = (e8 - row * GPR) * 8;
    if (row >= rows_pad) return;
    float v[8];
    if (row < nrows) {
        float4 a = *(const float4*)(X + (size_t)row * K + k0);
        float4 b = *(const float4*)(X + (size_t)row * K + k0 + 4);
        v[0] = a.x; v[1] = a.y; v[2] = a.z; v[3] = a.w;
        v[4] = b.x; v[5] = b.y; v[6] = b.z; v[7] = b.w;
        if (BN) {
            float4 s0 = *(const float4*)(bnsc + k0);
            float4 s1 = *(const float4*)(bnsc + k0 + 4);
            float4 h0 = *(const float4*)(bnsh + k0);
            float4 h1 = *(const float4*)(bnsh + k0 + 4);
            v[0] = fmaxf(0.f, fmaf(v[0], s0.x, h0.x));
            v[1] = fmaxf(0.f, fmaf(v[1], s0.y, h0.y));
            v[2] = fmaxf(0.f, fmaf(v[2], s0.z, h0.z));
            v[3] = fmaxf(0.f, fmaf(v[3], s0.w, h0.w));
            v[4] = fmaxf(0.f, fmaf(v[4], s1.x, h1.x));
            v[5] = fmaxf(0.f, fmaf(v[5], s1.y, h1.y));
            v[6] = fmaxf(0.f, fmaf(v[6], s1.z, h1.z));
            v[7] = fmaxf(0.f, fmaf(v[7], s1.w, h1.w));
        }
    } else {
#pragma unroll
        for (int j = 0; j < 8; ++j) v[j] = 0.f;
    }
    unsigned short h[8], l[8];
#pragma unroll
    for (int j = 0; j < 8; ++j) bsplit(v[j], h[j], l[j]);
    size_t f = (size_t)(row >> 4) * (K >> 5) + (k0 >> 5);
    int lane = ((k0 >> 3) & 3) * 16 + (row & 15);
    unsigned short* p = XF + f * 1024 + lane * 8;
    uint4 hv, lv;
    hv.x = h[0] | (h[1] << 16); hv.y = h[2] | (h[3] << 16);
    hv.z = h[4] | (h[5] << 16); hv.w = h[6] | (h[7] << 16);
    lv.x = l[0] | (l[1] << 16); lv.y = l[2] | (l[3] << 16);
    lv.z = l[4] | (l[5] << 16); lv.w = l[6] | (l[7] << 16);
    *(uint4*)p = hv;
    *(uint4*)(p + 512) = lv;
}

// ---------------------------------------------------------------------------
// prep_w: 4 fp32 weights [K][128] -> fragment-major hi/lo bf16 (B-operand).
// ---------------------------------------------------------------------------
template <int K>
__global__ __launch_bounds__(256) void prep_w(const float* __restrict__ W0,
                                              const float* __restrict__ W1,
                                              const float* __restrict__ W2,
                                              const float* __restrict__ W3,
                                              unsigned short* __restrict__ WF) {
    const float* W;
    switch (blockIdx.y) {
        case 0:  W = W0; break;
        case 1:  W = W1; break;
        case 2:  W = W2; break;
        default: W = W3; break;
    }
    const int GPC = K / 8;
    int e8 = blockIdx.x * 256 + threadIdx.x;
    if (e8 >= K * 16) return;
    int col = e8 / GPC;
    int k0 = (e8 - col * GPC) * 8;
    float v[8];
#pragma unroll
    for (int j = 0; j < 8; ++j) v[j] = W[(size_t)(k0 + j) * 128 + col];
    unsigned short h[8], l[8];
#pragma unroll
    for (int j = 0; j < 8; ++j) bsplit(v[j], h[j], l[j]);
    size_t f = (size_t)(col >> 4) * (K >> 5) + (k0 >> 5);
    int lane = ((k0 >> 3) & 3) * 16 + (col & 15);
    const size_t wstride = (size_t)8 * (K >> 5) * 1024;
    unsigned short* p = WF + blockIdx.y * wstride + f * 1024 + lane * 8;
    uint4 hv, lv;
    hv.x = h[0] | (h[1] << 16); hv.y = h[2] | (h[3] << 16);
    hv.z = h[4] | (h[5] << 16); hv.w = h[6] | (h[7] << 16);
    lv.x = l[0] | (l[1] << 16); lv.y = l[2] | (l[3] << 16);
    lv.z = l[4] | (l[5] << 16); lv.w = l[6] | (l[7] << 16);
    *(uint4*)p = hv;
    *(uint4*)(p + 512) = lv;
}

// ---------------------------------------------------------------------------
// LDS-free MFMA GEMM, 3-term split (hh + hl + lh). Each wave: 32x128 strip.
// y=0 -> q (fp32), y=1 -> k (bf16), y=2 -> v (bf16), y=3 -> skip/conv (fp32).
// ---------------------------------------------------------------------------
template <int K>
__global__ __launch_bounds__(256) void gemm_mfma(
    const unsigned short* __restrict__ XF, const unsigned short* __restrict__ WF,
    int n, int strips,
    const float* __restrict__ b0, const float* __restrict__ b1,
    const float* __restrict__ b2, const float* __restrict__ b3,
    float* __restrict__ oq, unsigned short* __restrict__ ok,
    unsigned short* __restrict__ ov, float* __restrict__ oskip) {
    const float* bias;
    switch (blockIdx.y) {
        case 0:  bias = b0; break;
        case 1:  bias = b1; break;
        case 2:  bias = b2; break;
        default: bias = b3; break;
    }
    constexpr int KB = K >> 5;
    const unsigned short* WFy = WF + (size_t)blockIdx.y * (8 * KB * 1024);
    int wid = (blockIdx.x * 256 + threadIdx.x) >> 6;
    int l = threadIdx.x & 63;
    if (wid >= strips) return;

    bf16x8 A[2][KB][2];
#pragma unroll
    for (int mf = 0; mf < 2; ++mf)
#pragma unroll
        for (int kb = 0; kb < KB; ++kb) {
            const unsigned short* p =
                XF + ((size_t)(wid * 2 + mf) * KB + kb) * 1024 + l * 8;
            A[mf][kb][0] = *(const bf16x8*)p;
            A[mf][kb][1] = *(const bf16x8*)(p + 512);
        }

#pragma unroll
    for (int nf = 0; nf < 8; ++nf) {
        bf16x8 B[KB][2];
#pragma unroll
        for (int kb = 0; kb < KB; ++kb) {
            const unsigned short* p = WFy + ((size_t)(nf * KB + kb)) * 1024 + l * 8;
            B[kb][0] = *(const bf16x8*)p;
            B[kb][1] = *(const bf16x8*)(p + 512);
        }
        f32x4 acc[2];
        acc[0] = (f32x4){0.f, 0.f, 0.f, 0.f};
        acc[1] = (f32x4){0.f, 0.f, 0.f, 0.f};
#pragma unroll
        for (int kb = 0; kb < KB; ++kb) {
#pragma unroll
            for (int mf = 0; mf < 2; ++mf) {
                acc[mf] = __builtin_amdgcn_mfma_f32_16x16x32_bf16(
                    A[mf][kb][0], B[kb][0], acc[mf], 0, 0, 0);
                acc[mf] = __builtin_amdgcn_mfma_f32_16x16x32_bf16(
                    A[mf][kb][0], B[kb][1], acc[mf], 0, 0, 0);
                acc[mf] = __builtin_amdgcn_mfma_f32_16x16x32_bf16(
                    A[mf][kb][1], B[kb][0], acc[mf], 0, 0, 0);
            }
        }
        int col = nf * 16 + (l & 15);
        float bb = bias[col];
        int rbase = wid * 32 + ((l >> 4) << 2);
        if (blockIdx.y == 0 || blockIdx.y == 3) {
            float* out = (blockIdx.y == 0) ? oq : oskip;
#pragma unroll
            for (int mf = 0; mf < 2; ++mf)
#pragma unroll
                for (int r = 0; r < 4; ++r) {
                    int row = rbase + mf * 16 + r;
                    if (row < n) out[(size_t)row * 128 + col] = acc[mf][r] + bb;
                }
        } else {
            unsigned short* out = (blockIdx.y == 1) ? ok : ov;
#pragma unroll
            for (int mf = 0; mf < 2; ++mf)
#pragma unroll
                for (int r = 0; r < 4; ++r) {
                    int row = rbase + mf * 16 + r;
                    if (row < n) out[(size_t)row * 128 + col] = bf16rne(acc[mf][r] + bb);
                }
        }
    }
}

// ---------------------------------------------------------------------------
// Per-target edge attention, online softmax, bf16 k/v gather (8B/lane/edge).
// ---------------------------------------------------------------------------
__global__ __launch_bounds__(256) void attn_kernel(
    const float* __restrict__ q, const unsigned short* __restrict__ k16,
    const unsigned short* __restrict__ v16,
    const int* __restrict__ rowptr, const int* __restrict__ esrc,
    float* __restrict__ h2, int n) {
    int wid = (blockIdx.x * blockDim.x + threadIdx.x) >> 6;
    int lane = threadIdx.x & 63;
    if (wid >= n) return;
    int f0 = lane * 2;
    float2 qv = *(const float2*)(q + (size_t)wid * 128 + f0);
    const float scale = 0.08838834764831845f;  // 1/sqrt(128)
    int beg = rowptr[wid], end = rowptr[wid + 1];
    if (beg == end) return;  // no in-edges: h2 stays = skip term (matches ref)
    float m = -3.402823466e38f, ssum = 0.f, acc0 = 0.f, acc1 = 0.f;
    int s0 = esrc[beg];
    unsigned kwN = *(const unsigned*)(k16 + (size_t)s0 * 128 + f0);
    unsigned vwN = *(const unsigned*)(v16 + (size_t)s0 * 128 + f0);
    for (int j = beg; j < end; ++j) {
        unsigned kw = kwN, vw = vwN;
        if (j + 1 < end) {
            int s = esrc[j + 1];
            kwN = *(const unsigned*)(k16 + (size_t)s * 128 + f0);
            vwN = *(const unsigned*)(v16 + (size_t)s * 128 + f0);
        }
        float kx = __uint_as_float(kw << 16);
        float ky = __uint_as_float(kw & 0xFFFF0000u);
        float d = qv.x * kx + qv.y * ky;
#pragma unroll
        for (int off = 32; off; off >>= 1) d += __shfl_xor(d, off);
        d *= scale;
        if (d > m) {   // uniform across wave
            float r = __expf(m - d);
            ssum *= r; acc0 *= r; acc1 *= r; m = d;
        }
        float w = __expf(d - m);
        ssum += w;
        acc0 += w * __uint_as_float(vw << 16);
        acc1 += w * __uint_as_float(vw & 0xFFFF0000u);
    }
    float inv = 1.f / ssum;
    float2* o = (float2*)(h2 + (size_t)wid * 128 + f0);
    float2 cur = *o;
    cur.x += acc0 * inv;
    cur.y += acc1 * inv;
    *o = cur;
}

// ---------------------------------------------------------------------------
// BatchNorm stats (apply fused into prep_x / pool)
// ---------------------------------------------------------------------------
__global__ __launch_bounds__(256) void bn_stats(const float* __restrict__ h2,
                                                float* __restrict__ psum,
                                                float* __restrict__ psq, int n) {
    int f = threadIdx.x & 127;
    int rp = threadIdx.x >> 7;
    float s = 0.f, s2 = 0.f;
    for (int r = blockIdx.x * 2 + rp; r < n; r += gridDim.x * 2) {
        float x = h2[(size_t)r * 128 + f];
        s += x;
        s2 += x * x;
    }
    __shared__ float sm[256], sm2[256];
    sm[threadIdx.x] = s;
    sm2[threadIdx.x] = s2;
    __syncthreads();
    if (rp == 0) {
        psum[blockIdx.x * 128 + f] = sm[f] + sm[128 + f];
        psq[blockIdx.x * 128 + f] = sm2[f] + sm2[128 + f];
    }
}

__global__ __launch_bounds__(512) void bn_finalize(const float* __restrict__ psum,
                                                   const float* __restrict__ psq,
                                                   const float* __restrict__ g,
                                                   const float* __restrict__ b,
                                                   float* __restrict__ scale,
                                                   float* __restrict__ shift, int n) {
    int f = threadIdx.x & 127, part = threadIdx.x >> 7;
    float s = 0.f, s2 = 0.f;
#pragma unroll 4
    for (int i = part; i < 256; i += 4) {
        s += psum[i * 128 + f];
        s2 += psq[i * 128 + f];
    }
    __shared__ float sa[512], sb[512];
    sa[threadIdx.x] = s;
    sb[threadIdx.x] = s2;
    __syncthreads();
    if (part == 0) {
        s = sa[f] + sa[128 + f] + sa[256 + f] + sa[384 + f];
        s2 = sb[f] + sb[128 + f] + sb[256 + f] + sb[384 + f];
        float inv_n = 1.f / (float)n;
        float mu = s * inv_n;
        float var = s2 * inv_n - mu * mu;
        float sc = g[f] * rsqrtf(var + 1e-5f);
        scale[f] = sc;
        shift[f] = b[f] - mu * sc;
    }
}

// ---------------------------------------------------------------------------
// Pool (fused last BN+ReLU) + head
// ---------------------------------------------------------------------------
__global__ __launch_bounds__(256) void pool_kernel(const float* __restrict__ h,
                                                   const float* __restrict__ bnsc,
                                                   const float* __restrict__ bnsh,
                                                   const int* __restrict__ batch,
                                                   float* __restrict__ pooled, int n) {
    int g = blockIdx.x;
    int lo = 0, hi = n;
    while (lo < hi) { int mid = (lo + hi) >> 1; if (batch[mid] < g) lo = mid + 1; else hi = mid; }
    int start = lo;
    lo = start; hi = n;
    while (lo < hi) { int mid = (lo + hi) >> 1; if (batch[mid] < g + 1) lo = mid + 1; else hi = mid; }
    int end = lo;
    int f = threadIdx.x & 127, rp = threadIdx.x >> 7;
    float sc = bnsc[f], sh = bnsh[f];
    float s = 0.f;
    for (int r = start + rp; r < end; r += 2)
        s += fmaxf(0.f, fmaf(h[(size_t)r * 128 + f], sc, sh));
    __shared__ float sm[256];
    sm[threadIdx.x] = s;
    __syncthreads();
    if (rp == 0) {
        float tot = sm[f] + sm[128 + f];
        float cnt = (float)(end - start);
        pooled[g * 128 + f] = tot / fmaxf(cnt, 1.f);
    }
}

__global__ void head_kernel(const float* __restrict__ pooled, const float* __restrict__ W,
                            const float* __restrict__ bias, float* __restrict__ out) {
    int g = blockIdx.x;
    int lane = threadIdx.x;  // 64
    float p0 = pooled[g * 128 + lane];
    float p1 = pooled[g * 128 + 64 + lane];
#pragma unroll
    for (int c = 0; c < C_CLASSES; ++c) {
        float d = p0 * W[lane * C_CLASSES + c] + p1 * W[(64 + lane) * C_CLASSES + c];
#pragma unroll
        for (int off = 32; off; off >>= 1) d += __shfl_xor(d, off);
        if (lane == 0) out[g * C_CLASSES + c] = d + bias[c];
    }
}

// ---------------------------------------------------------------------------
extern "C" void kernel_launch(void* const* d_in, const int* in_sizes, int n_in,
                              void* d_out, int out_size, void* d_ws, size_t ws_size,
                              hipStream_t stream) {
    const int N = in_sizes[0] / IN_DIM;       // 100000
    const int E = in_sizes[1] / 2;            // 600000

    const float* x     = (const float*)d_in[0];
    const int* ei      = (const int*)d_in[1];
    const int* src     = ei;
    const int* dst     = ei + E;
    const int* batch   = (const int*)d_in[2];
    const float* Wq1 = (const float*)d_in[3],  *bq1 = (const float*)d_in[4];
    const float* Wk1 = (const float*)d_in[5],  *bk1 = (const float*)d_in[6];
    const float* Wv1 = (const float*)d_in[7],  *bv1 = (const float*)d_in[8];
    const float* Ws1 = (const float*)d_in[9],  *bs1 = (const float*)d_in[10];
    const float* bn1g = (const float*)d_in[11], *bn1b = (const float*)d_in[12];
    const float* Wq = (const float*)d_in[13], *bq = (const float*)d_in[14];
    const float* Wk = (const float*)d_in[15], *bk = (const float*)d_in[16];
    const float* Wv = (const float*)d_in[17], *bv = (const float*)d_in[18];
    const float* Ws = (const float*)d_in[19], *bs = (const float*)d_in[20];
    const float* bng = (const float*)d_in[21], *bnb = (const float*)d_in[22];
    const float* linW = (const float*)d_in[23], *linb = (const float*)d_in[24];
    float* out = (float*)d_out;

    const int RB = (N + 127) / 128;           // 782 row-blocks
    const int rows_pad = RB * 128;            // 100096
    const int strips = rows_pad / 32;         // 3128

    // workspace layout
    char* w = (char*)d_ws;
    auto alloc = [&](size_t bytes) -> char* {
        char* p = w;
        w += (bytes + 255) & ~(size_t)255;
        return p;
    };
    const size_t NH = (size_t)N * H_DIM;
    float* q    = (float*)alloc(NH * 4);
    float* conv = (float*)alloc(NH * 4);   // conv output (skip + attn agg)
    unsigned short* k16 = (unsigned short*)alloc(NH * 2);
    unsigned short* v16 = (unsigned short*)alloc(NH * 2);
    unsigned short* XF = (unsigned short*)alloc((size_t)rows_pad * H_DIM * 2 * 2);  // 51.25MB
    unsigned short* WF = (unsigned short*)alloc((size_t)4 * H_DIM * H_DIM * 2 * 2); // 256KB
    float* psum = (float*)alloc(256 * 128 * 4);
    float* psq  = (float*)alloc(256 * 128 * 4);
    float* bnsc = (float*)alloc(128 * 4);
    float* bnsh = (float*)alloc(128 * 4);
    float* pooled = (float*)alloc(G_GRAPHS * H_DIM * 4);
    int* deg    = (int*)alloc((size_t)N * 4);
    int* rowptr = (int*)alloc((size_t)(N + 1) * 4);
    int* erank  = (int*)alloc((size_t)E * 4);
    int* esrc   = (int*)alloc((size_t)E * 4);
    int* bsum   = (int*)alloc(((size_t)(N + 255) / 256) * 4);

    const int nblk = (N + 255) / 256;
    const int egrid = (E + 255) / 256;

    // ---- CSR build (atomic pass records rank -> scatter is atomic-free)
    hipMemsetAsync(deg, 0, (size_t)N * 4, stream);
    count_deg<<<egrid, 256, 0, stream>>>(dst, deg, erank, E);
    scan1<<<nblk, 256, 0, stream>>>(deg, rowptr, bsum, N);
    scan2<<<1, 512, 0, stream>>>(bsum, nblk);
    scan3<<<nblk, 256, 0, stream>>>(rowptr, bsum, N);
    scatter_edges<<<egrid, 256, 0, stream>>>(src, dst, rowptr, erank, esrc, E);

    const int attn_blocks = (N + 3) / 4;

    // ---- layer 1 (K=64, raw input, no BN)
    {
        const int px_grid = rows_pad * IN_DIM / 8 / 256;
        prep_x<IN_DIM, false><<<px_grid, 256, 0, stream>>>(x, N, rows_pad, nullptr, nullptr, XF);
        prep_w<IN_DIM><<<dim3((IN_DIM * 16 + 255) / 256, 4), 256, 0, stream>>>(Wq1, Wk1, Wv1, Ws1, WF);
        gemm_mfma<IN_DIM><<<dim3(strips / 4, 4), 256, 0, stream>>>(
            XF, WF, N, strips, bq1, bk1, bv1, bs1, q, k16, v16, conv);
        attn_kernel<<<attn_blocks, 256, 0, stream>>>(q, k16, v16, rowptr, esrc, conv, N);
        bn_stats<<<256, 256, 0, stream>>>(conv, psum, psq, N);
        bn_finalize<<<1, 512, 0, stream>>>(psum, psq, bn1g, bn1b, bnsc, bnsh, N);
    }

    // ---- layers 2..4 (K=128, BN+ReLU fused into prep_x)
    for (int i = 0; i < L_LAYERS; ++i) {
        const size_t wo = (size_t)i * H_DIM * H_DIM;
        const size_t bo = (size_t)i * H_DIM;
        const int px_grid = rows_pad * H_DIM / 8 / 256;
        prep_x<H_DIM, true><<<px_grid, 256, 0, stream>>>(conv, N, rows_pad, bnsc, bnsh, XF);
        prep_w<H_DIM><<<dim3((H_DIM * 16 + 255) / 256, 4), 256, 0, stream>>>(
            Wq + wo, Wk + wo, Wv + wo, Ws + wo, WF);
        gemm_mfma<H_DIM><<<dim3(strips / 4, 4), 256, 0, stream>>>(
            XF, WF, N, strips, bq + bo, bk + bo, bv + bo, bs + bo, q, k16, v16, conv);
        attn_kernel<<<attn_blocks, 256, 0, stream>>>(q, k16, v16, rowptr, esrc, conv, N);
        bn_stats<<<256, 256, 0, stream>>>(conv, psum, psq, N);
        bn_finalize<<<1, 512, 0, stream>>>(psum, psq, bng + bo, bnb + bo, bnsc, bnsh, N);
    }

    // ---- pool (fused last BN+ReLU) + head
    pool_kernel<<<G_GRAPHS, 256, 0, stream>>>(conv, bnsc, bnsh, batch, pooled, N);
    head_kernel<<<G_GRAPHS, 64, 0, stream>>>(pooled, linW, linb, out);
}

// Round 5
// 1128.551 us; speedup vs baseline: 5.1659x; 1.0947x over previous
//
#include <hip/hip_runtime.h>
#include <hip/hip_bf16.h>

// Problem constants
#define IN_DIM 64
#define H_DIM 128
#define L_LAYERS 3
#define G_GRAPHS 256
#define C_CLASSES 10

typedef short bf16x8 __attribute__((ext_vector_type(8)));
typedef float f32x4 __attribute__((ext_vector_type(4)));

__device__ inline unsigned short bf16rne(float x) {
    unsigned v = __float_as_uint(x);
    v += 0x7FFFu + ((v >> 16) & 1u);
    return (unsigned short)(v >> 16);
}

// RNE split: x = hi + lo + eps, |lo| <= 2^-9 |x|, |eps| <~ 2^-17 |x|.
__device__ inline void bsplit(float x, unsigned short& h, unsigned short& l) {
    h = bf16rne(x);
    float hf = __uint_as_float((unsigned)h << 16);
    l = bf16rne(x - hf);
}

// ---------------------------------------------------------------------------
// CSR build (atomic-free scatter: count pass records per-edge rank)
// ---------------------------------------------------------------------------
__global__ void count_deg(const int* __restrict__ dst, int* __restrict__ deg,
                          int* __restrict__ erank, int e) {
    int i = blockIdx.x * blockDim.x + threadIdx.x;
    if (i < e) erank[i] = atomicAdd(&deg[dst[i]], 1);
}

__global__ __launch_bounds__(256) void scan1(const int* __restrict__ deg,
                                             int* __restrict__ rowptr,
                                             int* __restrict__ bsum, int n) {
    int i = blockIdx.x * 256 + threadIdx.x;
    int v = (i < n) ? deg[i] : 0;
    __shared__ int sm[256];
    sm[threadIdx.x] = v;
    __syncthreads();
    for (int off = 1; off < 256; off <<= 1) {
        int x = (threadIdx.x >= off) ? sm[threadIdx.x - off] : 0;
        __syncthreads();
        sm[threadIdx.x] += x;
        __syncthreads();
    }
    if (i < n) rowptr[i + 1] = sm[threadIdx.x];
    if (threadIdx.x == 255) bsum[blockIdx.x] = sm[255];
}

__global__ __launch_bounds__(512) void scan2(int* __restrict__ bsum, int nblk) {
    __shared__ int sm[512];
    int t = threadIdx.x;
    int v = (t < nblk) ? bsum[t] : 0;
    sm[t] = v;
    __syncthreads();
    for (int off = 1; off < 512; off <<= 1) {
        int x = (t >= off) ? sm[t - off] : 0;
        __syncthreads();
        sm[t] += x;
        __syncthreads();
    }
    if (t < nblk) bsum[t] = sm[t] - v;  // exclusive
}

__global__ void scan3(int* __restrict__ rowptr, const int* __restrict__ bsum, int n) {
    int i = blockIdx.x * 256 + threadIdx.x;
    if (i < n) rowptr[i + 1] += bsum[i >> 8];
    if (i == 0) rowptr[0] = 0;
}

__global__ void scatter_edges(const int* __restrict__ src, const int* __restrict__ dst,
                              const int* __restrict__ rowptr, const int* __restrict__ erank,
                              int* __restrict__ esrc, int e) {
    int i = blockIdx.x * blockDim.x + threadIdx.x;
    if (i < e) esrc[rowptr[dst[i]] + erank[i]] = src[i];
}

// ---------------------------------------------------------------------------
// prep_x: fp32 activations -> fragment-major hi/lo bf16, optional fused BN+ReLU.
// frag f = (row>>4)*(K>>5) + (k>>5); lane = ((k>>3)&3)*16 + (row&15); j = k&7.
// ---------------------------------------------------------------------------
template <int K, bool BN>
__global__ __launch_bounds__(256) void prep_x(const float* __restrict__ X, int nrows,
                                              int rows_pad,
                                              const float* __restrict__ bnsc,
                                              const float* __restrict__ bnsh,
                                              unsigned short* __restrict__ XF) {
    const int GPR = K / 8;
    int e8 = blockIdx.x * 256 + threadIdx.x;
    int row = e8 / GPR;
    int k0 = (e8 - row * GPR) * 8;
    if (row >= rows_pad) return;
    float v[8];
    if (row < nrows) {
        float4 a = *(const float4*)(X + (size_t)row * K + k0);
        float4 b = *(const float4*)(X + (size_t)row * K + k0 + 4);
        v[0] = a.x; v[1] = a.y; v[2] = a.z; v[3] = a.w;
        v[4] = b.x; v[5] = b.y; v[6] = b.z; v[7] = b.w;
        if (BN) {
            float4 s0 = *(const float4*)(bnsc + k0);
            float4 s1 = *(const float4*)(bnsc + k0 + 4);
            float4 h0 = *(const float4*)(bnsh + k0);
            float4 h1 = *(const float4*)(bnsh + k0 + 4);
            v[0] = fmaxf(0.f, fmaf(v[0], s0.x, h0.x));
            v[1] = fmaxf(0.f, fmaf(v[1], s0.y, h0.y));
            v[2] = fmaxf(0.f, fmaf(v[2], s0.z, h0.z));
            v[3] = fmaxf(0.f, fmaf(v[3], s0.w, h0.w));
            v[4] = fmaxf(0.f, fmaf(v[4], s1.x, h1.x));
            v[5] = fmaxf(0.f, fmaf(v[5], s1.y, h1.y));
            v[6] = fmaxf(0.f, fmaf(v[6], s1.z, h1.z));
            v[7] = fmaxf(0.f, fmaf(v[7], s1.w, h1.w));
        }
    } else {
#pragma unroll
        for (int j = 0; j < 8; ++j) v[j] = 0.f;
    }
    unsigned short h[8], l[8];
#pragma unroll
    for (int j = 0; j < 8; ++j) bsplit(v[j], h[j], l[j]);
    size_t f = (size_t)(row >> 4) * (K >> 5) + (k0 >> 5);
    int lane = ((k0 >> 3) & 3) * 16 + (row & 15);
    unsigned short* p = XF + f * 1024 + lane * 8;
    uint4 hv, lv;
    hv.x = h[0] | (h[1] << 16); hv.y = h[2] | (h[3] << 16);
    hv.z = h[4] | (h[5] << 16); hv.w = h[6] | (h[7] << 16);
    lv.x = l[0] | (l[1] << 16); lv.y = l[2] | (l[3] << 16);
    lv.z = l[4] | (l[5] << 16); lv.w = l[6] | (l[7] << 16);
    *(uint4*)p = hv;
    *(uint4*)(p + 512) = lv;
}

// ---------------------------------------------------------------------------
// prep_w: 4 fp32 weights [K][128] -> fragment-major hi/lo bf16 (B-operand).
// ---------------------------------------------------------------------------
template <int K>
__global__ __launch_bounds__(256) void prep_w(const float* __restrict__ W0,
                                              const float* __restrict__ W1,
                                              const float* __restrict__ W2,
                                              const float* __restrict__ W3,
                                              unsigned short* __restrict__ WF) {
    const float* W;
    switch (blockIdx.y) {
        case 0:  W = W0; break;
        case 1:  W = W1; break;
        case 2:  W = W2; break;
        default: W = W3; break;
    }
    const int GPC = K / 8;
    int e8 = blockIdx.x * 256 + threadIdx.x;
    if (e8 >= K * 16) return;
    int col = e8 / GPC;
    int k0 = (e8 - col * GPC) * 8;
    float v[8];
#pragma unroll
    for (int j = 0; j < 8; ++j) v[j] = W[(size_t)(k0 + j) * 128 + col];
    unsigned short h[8], l[8];
#pragma unroll
    for (int j = 0; j < 8; ++j) bsplit(v[j], h[j], l[j]);
    size_t f = (size_t)(col >> 4) * (K >> 5) + (k0 >> 5);
    int lane = ((k0 >> 3) & 3) * 16 + (col & 15);
    const size_t wstride = (size_t)8 * (K >> 5) * 1024;
    unsigned short* p = WF + blockIdx.y * wstride + f * 1024 + lane * 8;
    uint4 hv, lv;
    hv.x = h[0] | (h[1] << 16); hv.y = h[2] | (h[3] << 16);
    hv.z = h[4] | (h[5] << 16); hv.w = h[6] | (h[7] << 16);
    lv.x = l[0] | (l[1] << 16); lv.y = l[2] | (l[3] << 16);
    lv.z = l[4] | (l[5] << 16); lv.w = l[6] | (l[7] << 16);
    *(uint4*)p = hv;
    *(uint4*)(p + 512) = lv;
}

// ---------------------------------------------------------------------------
// Merged LDS-free MFMA GEMM: ONE kernel computes q/k/v/skip.  A-fragments are
// loaded once per wave and reused across all 4 weight sets (was 4x re-read).
// 3-term split (hh + hl + lh). Each wave: 32-row x 128-col strip x 4 outputs.
// ---------------------------------------------------------------------------
template <int K>
__global__ __launch_bounds__(256) void gemm_mfma(
    const unsigned short* __restrict__ XF, const unsigned short* __restrict__ WF,
    int n, int strips,
    const float* __restrict__ b0, const float* __restrict__ b1,
    const float* __restrict__ b2, const float* __restrict__ b3,
    float* __restrict__ oq, unsigned short* __restrict__ ok,
    unsigned short* __restrict__ ov, float* __restrict__ oskip) {
    constexpr int KB = K >> 5;
    int wid = (blockIdx.x * 256 + threadIdx.x) >> 6;
    int l = threadIdx.x & 63;
    if (wid >= strips) return;

    bf16x8 A[2][KB][2];
#pragma unroll
    for (int mf = 0; mf < 2; ++mf)
#pragma unroll
        for (int kb = 0; kb < KB; ++kb) {
            const unsigned short* p =
                XF + ((size_t)(wid * 2 + mf) * KB + kb) * 1024 + l * 8;
            A[mf][kb][0] = *(const bf16x8*)p;
            A[mf][kb][1] = *(const bf16x8*)(p + 512);
        }

    const int rbase = wid * 32 + ((l >> 4) << 2);
#pragma unroll
    for (int nf = 0; nf < 8; ++nf) {
        const int col = nf * 16 + (l & 15);
#pragma unroll
        for (int y = 0; y < 4; ++y) {
            const float* bias = (y == 0) ? b0 : (y == 1) ? b1 : (y == 2) ? b2 : b3;
            const unsigned short* WFy = WF + (size_t)y * (8 * KB * 1024);
            bf16x8 B[KB][2];
#pragma unroll
            for (int kb = 0; kb < KB; ++kb) {
                const unsigned short* p = WFy + ((size_t)(nf * KB + kb)) * 1024 + l * 8;
                B[kb][0] = *(const bf16x8*)p;
                B[kb][1] = *(const bf16x8*)(p + 512);
            }
            f32x4 acc[2];
            acc[0] = (f32x4){0.f, 0.f, 0.f, 0.f};
            acc[1] = (f32x4){0.f, 0.f, 0.f, 0.f};
#pragma unroll
            for (int kb = 0; kb < KB; ++kb) {
#pragma unroll
                for (int mf = 0; mf < 2; ++mf) {
                    acc[mf] = __builtin_amdgcn_mfma_f32_16x16x32_bf16(
                        A[mf][kb][0], B[kb][0], acc[mf], 0, 0, 0);
                    acc[mf] = __builtin_amdgcn_mfma_f32_16x16x32_bf16(
                        A[mf][kb][0], B[kb][1], acc[mf], 0, 0, 0);
                    acc[mf] = __builtin_amdgcn_mfma_f32_16x16x32_bf16(
                        A[mf][kb][1], B[kb][0], acc[mf], 0, 0, 0);
                }
            }
            float bb = bias[col];
            if (y == 0 || y == 3) {
                float* outp = (y == 0) ? oq : oskip;
#pragma unroll
                for (int mf = 0; mf < 2; ++mf)
#pragma unroll
                    for (int r = 0; r < 4; ++r) {
                        int row = rbase + mf * 16 + r;
                        if (row < n) outp[(size_t)row * 128 + col] = acc[mf][r] + bb;
                    }
            } else {
                unsigned short* outp = (y == 1) ? ok : ov;
#pragma unroll
                for (int mf = 0; mf < 2; ++mf)
#pragma unroll
                    for (int r = 0; r < 4; ++r) {
                        int row = rbase + mf * 16 + r;
                        if (row < n) outp[(size_t)row * 128 + col] = bf16rne(acc[mf][r] + bb);
                    }
            }
        }
    }
}

// ---------------------------------------------------------------------------
// Per-target edge attention, online softmax, bf16 k/v gather.
// Chunk-4 double-buffered prefetch: 8 gathers in flight while processing the
// previous 4 edges (was 1-deep / 2 in flight -> latency-bound at 107us).
// ---------------------------------------------------------------------------
__global__ __launch_bounds__(256) void attn_kernel(
    const float* __restrict__ q, const unsigned short* __restrict__ k16,
    const unsigned short* __restrict__ v16,
    const int* __restrict__ rowptr, const int* __restrict__ esrc,
    float* __restrict__ h2, int n) {
    int wid = (blockIdx.x * blockDim.x + threadIdx.x) >> 6;
    int lane = threadIdx.x & 63;
    if (wid >= n) return;
    int f0 = lane * 2;
    float2 qv = *(const float2*)(q + (size_t)wid * 128 + f0);
    const float scale = 0.08838834764831845f;  // 1/sqrt(128)
    int beg = rowptr[wid], end = rowptr[wid + 1];
    if (beg == end) return;  // no in-edges: h2 stays = skip term (matches ref)
    float m = -3.402823466e38f, ssum = 0.f, acc0 = 0.f, acc1 = 0.f;

    unsigned kA[4], vA[4];
#pragma unroll
    for (int c = 0; c < 4; ++c) {
        int jj = beg + c; jj = jj < end ? jj : end - 1;
        int s = esrc[jj];
        kA[c] = *(const unsigned*)(k16 + (size_t)s * 128 + f0);
        vA[c] = *(const unsigned*)(v16 + (size_t)s * 128 + f0);
    }
    for (int j = beg; j < end; j += 4) {
        unsigned kB[4], vB[4];
        if (j + 4 < end) {
#pragma unroll
            for (int c = 0; c < 4; ++c) {
                int jj = j + 4 + c; jj = jj < end ? jj : end - 1;
                int s = esrc[jj];
                kB[c] = *(const unsigned*)(k16 + (size_t)s * 128 + f0);
                vB[c] = *(const unsigned*)(v16 + (size_t)s * 128 + f0);
            }
        } else {
#pragma unroll
            for (int c = 0; c < 4; ++c) { kB[c] = 0; vB[c] = 0; }
        }
        int cnt = end - j;  // >=1; process min(4,cnt)
#pragma unroll
        for (int c = 0; c < 4; ++c) {
            if (c < cnt) {
                unsigned kw = kA[c], vw = vA[c];
                float kx = __uint_as_float(kw << 16);
                float ky = __uint_as_float(kw & 0xFFFF0000u);
                float d = qv.x * kx + qv.y * ky;
#pragma unroll
                for (int off = 32; off; off >>= 1) d += __shfl_xor(d, off);
                d *= scale;
                if (d > m) {   // uniform across wave
                    float r = __expf(m - d);
                    ssum *= r; acc0 *= r; acc1 *= r; m = d;
                }
                float w = __expf(d - m);
                ssum += w;
                acc0 += w * __uint_as_float(vw << 16);
                acc1 += w * __uint_as_float(vw & 0xFFFF0000u);
            }
        }
#pragma unroll
        for (int c = 0; c < 4; ++c) { kA[c] = kB[c]; vA[c] = vB[c]; }
    }
    float inv = 1.f / ssum;
    float2* o = (float2*)(h2 + (size_t)wid * 128 + f0);
    float2 cur = *o;
    cur.x += acc0 * inv;
    cur.y += acc1 * inv;
    *o = cur;
}

// ---------------------------------------------------------------------------
// BatchNorm stats (apply fused into prep_x / pool)
// ---------------------------------------------------------------------------
__global__ __launch_bounds__(256) void bn_stats(const float* __restrict__ h2,
                                                float* __restrict__ psum,
                                                float* __restrict__ psq, int n) {
    int f = threadIdx.x & 127;
    int rp = threadIdx.x >> 7;
    float s = 0.f, s2 = 0.f;
    for (int r = blockIdx.x * 2 + rp; r < n; r += gridDim.x * 2) {
        float x = h2[(size_t)r * 128 + f];
        s += x;
        s2 += x * x;
    }
    __shared__ float sm[256], sm2[256];
    sm[threadIdx.x] = s;
    sm2[threadIdx.x] = s2;
    __syncthreads();
    if (rp == 0) {
        psum[blockIdx.x * 128 + f] = sm[f] + sm[128 + f];
        psq[blockIdx.x * 128 + f] = sm2[f] + sm2[128 + f];
    }
}

__global__ __launch_bounds__(512) void bn_finalize(const float* __restrict__ psum,
                                                   const float* __restrict__ psq,
                                                   const float* __restrict__ g,
                                                   const float* __restrict__ b,
                                                   float* __restrict__ scale,
                                                   float* __restrict__ shift, int n) {
    int f = threadIdx.x & 127, part = threadIdx.x >> 7;
    float s = 0.f, s2 = 0.f;
#pragma unroll 4
    for (int i = part; i < 256; i += 4) {
        s += psum[i * 128 + f];
        s2 += psq[i * 128 + f];
    }
    __shared__ float sa[512], sb[512];
    sa[threadIdx.x] = s;
    sb[threadIdx.x] = s2;
    __syncthreads();
    if (part == 0) {
        s = sa[f] + sa[128 + f] + sa[256 + f] + sa[384 + f];
        s2 = sb[f] + sb[128 + f] + sb[256 + f] + sb[384 + f];
        float inv_n = 1.f / (float)n;
        float mu = s * inv_n;
        float var = s2 * inv_n - mu * mu;
        float sc = g[f] * rsqrtf(var + 1e-5f);
        scale[f] = sc;
        shift[f] = b[f] - mu * sc;
    }
}

// ---------------------------------------------------------------------------
// Pool (fused last BN+ReLU) + head
// ---------------------------------------------------------------------------
__global__ __launch_bounds__(256) void pool_kernel(const float* __restrict__ h,
                                                   const float* __restrict__ bnsc,
                                                   const float* __restrict__ bnsh,
                                                   const int* __restrict__ batch,
                                                   float* __restrict__ pooled, int n) {
    int g = blockIdx.x;
    int lo = 0, hi = n;
    while (lo < hi) { int mid = (lo + hi) >> 1; if (batch[mid] < g) lo = mid + 1; else hi = mid; }
    int start = lo;
    lo = start; hi = n;
    while (lo < hi) { int mid = (lo + hi) >> 1; if (batch[mid] < g + 1) lo = mid + 1; else hi = mid; }
    int end = lo;
    int f = threadIdx.x & 127, rp = threadIdx.x >> 7;
    float sc = bnsc[f], sh = bnsh[f];
    float s = 0.f;
    for (int r = start + rp; r < end; r += 2)
        s += fmaxf(0.f, fmaf(h[(size_t)r * 128 + f], sc, sh));
    __shared__ float sm[256];
    sm[threadIdx.x] = s;
    __syncthreads();
    if (rp == 0) {
        float tot = sm[f] + sm[128 + f];
        float cnt = (float)(end - start);
        pooled[g * 128 + f] = tot / fmaxf(cnt, 1.f);
    }
}

__global__ void head_kernel(const float* __restrict__ pooled, const float* __restrict__ W,
                            const float* __restrict__ bias, float* __restrict__ out) {
    int g = blockIdx.x;
    int lane = threadIdx.x;  // 64
    float p0 = pooled[g * 128 + lane];
    float p1 = pooled[g * 128 + 64 + lane];
#pragma unroll
    for (int c = 0; c < C_CLASSES; ++c) {
        float d = p0 * W[lane * C_CLASSES + c] + p1 * W[(64 + lane) * C_CLASSES + c];
#pragma unroll
        for (int off = 32; off; off >>= 1) d += __shfl_xor(d, off);
        if (lane == 0) out[g * C_CLASSES + c] = d + bias[c];
    }
}

// ---------------------------------------------------------------------------
extern "C" void kernel_launch(void* const* d_in, const int* in_sizes, int n_in,
                              void* d_out, int out_size, void* d_ws, size_t ws_size,
                              hipStream_t stream) {
    const int N = in_sizes[0] / IN_DIM;       // 100000
    const int E = in_sizes[1] / 2;            // 600000

    const float* x     = (const float*)d_in[0];
    const int* ei      = (const int*)d_in[1];
    const int* src     = ei;
    const int* dst     = ei + E;
    const int* batch   = (const int*)d_in[2];
    const float* Wq1 = (const float*)d_in[3],  *bq1 = (const float*)d_in[4];
    const float* Wk1 = (const float*)d_in[5],  *bk1 = (const float*)d_in[6];
    const float* Wv1 = (const float*)d_in[7],  *bv1 = (const float*)d_in[8];
    const float* Ws1 = (const float*)d_in[9],  *bs1 = (const float*)d_in[10];
    const float* bn1g = (const float*)d_in[11], *bn1b = (const float*)d_in[12];
    const float* Wq = (const float*)d_in[13], *bq = (const float*)d_in[14];
    const float* Wk = (const float*)d_in[15], *bk = (const float*)d_in[16];
    const float* Wv = (const float*)d_in[17], *bv = (const float*)d_in[18];
    const float* Ws = (const float*)d_in[19], *bs = (const float*)d_in[20];
    const float* bng = (const float*)d_in[21], *bnb = (const float*)d_in[22];
    const float* linW = (const float*)d_in[23], *linb = (const float*)d_in[24];
    float* out = (float*)d_out;

    const int RB = (N + 127) / 128;           // 782 row-blocks
    const int rows_pad = RB * 128;            // 100096
    const int strips = rows_pad / 32;         // 3128

    // workspace layout
    char* w = (char*)d_ws;
    auto alloc = [&](size_t bytes) -> char* {
        char* p = w;
        w += (bytes + 255) & ~(size_t)255;
        return p;
    };
    const size_t NH = (size_t)N * H_DIM;
    float* q    = (float*)alloc(NH * 4);
    float* conv = (float*)alloc(NH * 4);   // conv output (skip + attn agg)
    unsigned short* k16 = (unsigned short*)alloc(NH * 2);
    unsigned short* v16 = (unsigned short*)alloc(NH * 2);
    unsigned short* XF = (unsigned short*)alloc((size_t)rows_pad * H_DIM * 2 * 2);  // 51.25MB
    unsigned short* WF = (unsigned short*)alloc((size_t)4 * H_DIM * H_DIM * 2 * 2); // 256KB
    float* psum = (float*)alloc(256 * 128 * 4);
    float* psq  = (float*)alloc(256 * 128 * 4);
    float* bnsc = (float*)alloc(128 * 4);
    float* bnsh = (float*)alloc(128 * 4);
    float* pooled = (float*)alloc(G_GRAPHS * H_DIM * 4);
    int* deg    = (int*)alloc((size_t)N * 4);
    int* rowptr = (int*)alloc((size_t)(N + 1) * 4);
    int* erank  = (int*)alloc((size_t)E * 4);
    int* esrc   = (int*)alloc((size_t)E * 4);
    int* bsum   = (int*)alloc(((size_t)(N + 255) / 256) * 4);

    const int nblk = (N + 255) / 256;
    const int egrid = (E + 255) / 256;

    // ---- CSR build (atomic pass records rank -> scatter is atomic-free)
    hipMemsetAsync(deg, 0, (size_t)N * 4, stream);
    count_deg<<<egrid, 256, 0, stream>>>(dst, deg, erank, E);
    scan1<<<nblk, 256, 0, stream>>>(deg, rowptr, bsum, N);
    scan2<<<1, 512, 0, stream>>>(bsum, nblk);
    scan3<<<nblk, 256, 0, stream>>>(rowptr, bsum, N);
    scatter_edges<<<egrid, 256, 0, stream>>>(src, dst, rowptr, erank, esrc, E);

    const int attn_blocks = (N + 3) / 4;
    const int gemm_blocks = (strips + 3) / 4;   // 4 waves (strips) per block

    // ---- layer 1 (K=64, raw input, no BN)
    {
        const int px_grid = rows_pad * IN_DIM / 8 / 256;
        prep_x<IN_DIM, false><<<px_grid, 256, 0, stream>>>(x, N, rows_pad, nullptr, nullptr, XF);
        prep_w<IN_DIM><<<dim3((IN_DIM * 16 + 255) / 256, 4), 256, 0, stream>>>(Wq1, Wk1, Wv1, Ws1, WF);
        gemm_mfma<IN_DIM><<<gemm_blocks, 256, 0, stream>>>(
            XF, WF, N, strips, bq1, bk1, bv1, bs1, q, k16, v16, conv);
        attn_kernel<<<attn_blocks, 256, 0, stream>>>(q, k16, v16, rowptr, esrc, conv, N);
        bn_stats<<<256, 256, 0, stream>>>(conv, psum, psq, N);
        bn_finalize<<<1, 512, 0, stream>>>(psum, psq, bn1g, bn1b, bnsc, bnsh, N);
    }

    // ---- layers 2..4 (K=128, BN+ReLU fused into prep_x)
    for (int i = 0; i < L_LAYERS; ++i) {
        const size_t wo = (size_t)i * H_DIM * H_DIM;
        const size_t bo = (size_t)i * H_DIM;
        const int px_grid = rows_pad * H_DIM / 8 / 256;
        prep_x<H_DIM, true><<<px_grid, 256, 0, stream>>>(conv, N, rows_pad, bnsc, bnsh, XF);
        prep_w<H_DIM><<<dim3((H_DIM * 16 + 255) / 256, 4), 256, 0, stream>>>(
            Wq + wo, Wk + wo, Wv + wo, Ws + wo, WF);
        gemm_mfma<H_DIM><<<gemm_blocks, 256, 0, stream>>>(
            XF, WF, N, strips, bq + bo, bk + bo, bv + bo, bs + bo, q, k16, v16, conv);
        attn_kernel<<<attn_blocks, 256, 0, stream>>>(q, k16, v16, rowptr, esrc, conv, N);
        bn_stats<<<256, 256, 0, stream>>>(conv, psum, psq, N);
        bn_finalize<<<1, 512, 0, stream>>>(psum, psq, bng + bo, bnb + bo, bnsc, bnsh, N);
    }

    // ---- pool (fused last BN+ReLU) + head
    pool_kernel<<<G_GRAPHS, 256, 0, stream>>>(conv, bnsc, bnsh, batch, pooled, N);
    head_kernel<<<G_GRAPHS, 64, 0, stream>>>(pooled, linW, linb, out);
}

// Round 7
// 1038.776 us; speedup vs baseline: 5.6124x; 1.0864x over previous
//
#include <hip/hip_runtime.h>
#include <hip/hip_bf16.h>

// Problem constants
#define IN_DIM 64
#define H_DIM 128
#define L_LAYERS 3
#define G_GRAPHS 256
#define C_CLASSES 10

typedef short bf16x8 __attribute__((ext_vector_type(8)));
typedef float f32x4 __attribute__((ext_vector_type(4)));

__device__ inline unsigned short bf16rne(float x) {
    unsigned v = __float_as_uint(x);
    v += 0x7FFFu + ((v >> 16) & 1u);
    return (unsigned short)(v >> 16);
}

// RNE split: x = hi + lo + eps, |eps| <~ 2^-17 |x|.
__device__ inline void bsplit(float x, unsigned short& h, unsigned short& l) {
    h = bf16rne(x);
    float hf = __uint_as_float((unsigned)h << 16);
    l = bf16rne(x - hf);
}

// ---------------------------------------------------------------------------
// CSR build (atomic-free scatter: count pass records per-edge rank)
// ---------------------------------------------------------------------------
__global__ void count_deg(const int* __restrict__ dst, int* __restrict__ deg,
                          int* __restrict__ erank, int e) {
    int i = blockIdx.x * blockDim.x + threadIdx.x;
    if (i < e) erank[i] = atomicAdd(&deg[dst[i]], 1);
}

__global__ __launch_bounds__(256) void scan1(const int* __restrict__ deg,
                                             int* __restrict__ rowptr,
                                             int* __restrict__ bsum, int n) {
    int i = blockIdx.x * 256 + threadIdx.x;
    int v = (i < n) ? deg[i] : 0;
    __shared__ int sm[256];
    sm[threadIdx.x] = v;
    __syncthreads();
    for (int off = 1; off < 256; off <<= 1) {
        int x = (threadIdx.x >= off) ? sm[threadIdx.x - off] : 0;
        __syncthreads();
        sm[threadIdx.x] += x;
        __syncthreads();
    }
    if (i < n) rowptr[i + 1] = sm[threadIdx.x];
    if (threadIdx.x == 255) bsum[blockIdx.x] = sm[255];
}

__global__ __launch_bounds__(512) void scan2(int* __restrict__ bsum, int nblk) {
    __shared__ int sm[512];
    int t = threadIdx.x;
    int v = (t < nblk) ? bsum[t] : 0;
    sm[t] = v;
    __syncthreads();
    for (int off = 1; off < 512; off <<= 1) {
        int x = (t >= off) ? sm[t - off] : 0;
        __syncthreads();
        sm[t] += x;
        __syncthreads();
    }
    if (t < nblk) bsum[t] = sm[t] - v;  // exclusive
}

__global__ void scan3(int* __restrict__ rowptr, const int* __restrict__ bsum, int n) {
    int i = blockIdx.x * 256 + threadIdx.x;
    if (i < n) rowptr[i + 1] += bsum[i >> 8];
    if (i == 0) rowptr[0] = 0;
}

__global__ void scatter_edges(const int* __restrict__ src, const int* __restrict__ dst,
                              const int* __restrict__ rowptr, const int* __restrict__ erank,
                              int* __restrict__ esrc, int e) {
    int i = blockIdx.x * blockDim.x + threadIdx.x;
    if (i < e) esrc[rowptr[dst[i]] + erank[i]] = src[i];
}

// ---------------------------------------------------------------------------
// prep_w: fp32 weights [K][128] -> fragment-major hi/lo bf16 (B-operand).
// frag f = (col>>4)*(K>>5) + (k>>5); lane = ((k>>3)&3)*16 + (col&15); j = k&7.
// Two launches cover all 16 matrices up-front (weights don't depend on acts).
// ---------------------------------------------------------------------------
template <int K>
__device__ inline void prep_w_one(const float* __restrict__ W,
                                  unsigned short* __restrict__ WFm, int e8) {
    const int GPC = K / 8;
    if (e8 >= K * 16) return;
    int col = e8 / GPC;
    int k0 = (e8 - col * GPC) * 8;
    float v[8];
#pragma unroll
    for (int j = 0; j < 8; ++j) v[j] = W[(size_t)(k0 + j) * 128 + col];
    unsigned short h[8], l[8];
#pragma unroll
    for (int j = 0; j < 8; ++j) bsplit(v[j], h[j], l[j]);
    size_t f = (size_t)(col >> 4) * (K >> 5) + (k0 >> 5);
    int lane = ((k0 >> 3) & 3) * 16 + (col & 15);
    unsigned short* p = WFm + f * 1024 + lane * 8;
    uint4 hv, lv;
    hv.x = h[0] | (h[1] << 16); hv.y = h[2] | (h[3] << 16);
    hv.z = h[4] | (h[5] << 16); hv.w = h[6] | (h[7] << 16);
    lv.x = l[0] | (l[1] << 16); lv.y = l[2] | (l[3] << 16);
    lv.z = l[4] | (l[5] << 16); lv.w = l[6] | (l[7] << 16);
    *(uint4*)p = hv;
    *(uint4*)(p + 512) = lv;
}

__global__ __launch_bounds__(256) void prep_w64(const float* __restrict__ W0,
                                                const float* __restrict__ W1,
                                                const float* __restrict__ W2,
                                                const float* __restrict__ W3,
                                                unsigned short* __restrict__ WF) {
    const float* W = (blockIdx.y == 0) ? W0 : (blockIdx.y == 1) ? W1
                   : (blockIdx.y == 2) ? W2 : W3;
    prep_w_one<IN_DIM>(W, WF + (size_t)blockIdx.y * 16384,
                       blockIdx.x * 256 + threadIdx.x);
}

__global__ __launch_bounds__(256) void prep_w128(const float* __restrict__ Wq,
                                                 const float* __restrict__ Wk,
                                                 const float* __restrict__ Wv,
                                                 const float* __restrict__ Ws,
                                                 unsigned short* __restrict__ WF) {
    int layer = blockIdx.y >> 2, mat = blockIdx.y & 3;
    const float* base = (mat == 0) ? Wq : (mat == 1) ? Wk : (mat == 2) ? Wv : Ws;
    const float* W = base + (size_t)layer * H_DIM * H_DIM;
    unsigned short* o = WF + 65536 + (size_t)blockIdx.y * 32768;
    prep_w_one<H_DIM>(W, o, blockIdx.x * 256 + threadIdx.x);
}

// ---------------------------------------------------------------------------
// Fused GEMM: reads fp32 activations directly (BN+ReLU+hi/lo split in-reg; the
// prep_x kernel and XF round-trip are gone). One kernel -> q/k/v/skip.
// LDS-free, 3-term split (hh+hl+lh). Each wave: 32-row x 128-col strip.
// k/v written bf16 into interleaved kv buffer [node][k 0..128 | v 128..256].
// ---------------------------------------------------------------------------
template <int K, bool BN>
__global__ __launch_bounds__(256) void gemm_fused(
    const float* __restrict__ X, const unsigned short* __restrict__ WF,
    int n, int strips,
    const float* __restrict__ bnsc, const float* __restrict__ bnsh,
    const float* __restrict__ b0, const float* __restrict__ b1,
    const float* __restrict__ b2, const float* __restrict__ b3,
    float* __restrict__ oq, unsigned short* __restrict__ okv,
    float* __restrict__ oskip) {
    constexpr int KB = K >> 5;
    int wid = (blockIdx.x * 256 + threadIdx.x) >> 6;
    int l = threadIdx.x & 63;
    if (wid >= strips) return;
    const int r16 = l & 15;
    const int ko8 = (l >> 4) * 8;

    // A fragments: load fp32 rows in fragment order, BN+ReLU, split hi/lo.
    bf16x8 A[2][KB][2];
#pragma unroll
    for (int kb = 0; kb < KB; ++kb) {
        float sc[8], sh[8];
        if (BN) {
            *(float4*)sc       = *(const float4*)(bnsc + kb * 32 + ko8);
            *(float4*)(sc + 4) = *(const float4*)(bnsc + kb * 32 + ko8 + 4);
            *(float4*)sh       = *(const float4*)(bnsh + kb * 32 + ko8);
            *(float4*)(sh + 4) = *(const float4*)(bnsh + kb * 32 + ko8 + 4);
        }
#pragma unroll
        for (int mf = 0; mf < 2; ++mf) {
            int row = wid * 32 + mf * 16 + r16;
            int rowc = row < n ? row : n - 1;
            const float* px = X + (size_t)rowc * K + kb * 32 + ko8;
            float v[8];
            *(float4*)v       = *(const float4*)px;
            *(float4*)(v + 4) = *(const float4*)(px + 4);
            if (BN) {
#pragma unroll
                for (int j = 0; j < 8; ++j) v[j] = fmaxf(0.f, fmaf(v[j], sc[j], sh[j]));
            }
            bf16x8 hi, lo;
#pragma unroll
            for (int j = 0; j < 8; ++j) {
                unsigned short h, l2;
                bsplit(v[j], h, l2);
                hi[j] = (short)h; lo[j] = (short)l2;
            }
            A[mf][kb][0] = hi;
            A[mf][kb][1] = lo;
        }
    }

    const int rbase = wid * 32 + ((l >> 4) << 2);
#pragma unroll
    for (int nf = 0; nf < 8; ++nf) {
        const int col = nf * 16 + (l & 15);
#pragma unroll
        for (int y = 0; y < 4; ++y) {
            const float* bias = (y == 0) ? b0 : (y == 1) ? b1 : (y == 2) ? b2 : b3;
            const unsigned short* WFy = WF + (size_t)y * (8 * KB * 1024);
            bf16x8 B[KB][2];
#pragma unroll
            for (int kb = 0; kb < KB; ++kb) {
                const unsigned short* p = WFy + ((size_t)(nf * KB + kb)) * 1024 + l * 8;
                B[kb][0] = *(const bf16x8*)p;
                B[kb][1] = *(const bf16x8*)(p + 512);
            }
            f32x4 acc[2];
            acc[0] = (f32x4){0.f, 0.f, 0.f, 0.f};
            acc[1] = (f32x4){0.f, 0.f, 0.f, 0.f};
#pragma unroll
            for (int kb = 0; kb < KB; ++kb) {
#pragma unroll
                for (int mf = 0; mf < 2; ++mf) {
                    acc[mf] = __builtin_amdgcn_mfma_f32_16x16x32_bf16(
                        A[mf][kb][0], B[kb][0], acc[mf], 0, 0, 0);
                    acc[mf] = __builtin_amdgcn_mfma_f32_16x16x32_bf16(
                        A[mf][kb][0], B[kb][1], acc[mf], 0, 0, 0);
                    acc[mf] = __builtin_amdgcn_mfma_f32_16x16x32_bf16(
                        A[mf][kb][1], B[kb][0], acc[mf], 0, 0, 0);
                }
            }
            float bb = bias[col];
            if (y == 0 || y == 3) {
                float* outp = (y == 0) ? oq : oskip;
#pragma unroll
                for (int mf = 0; mf < 2; ++mf)
#pragma unroll
                    for (int r = 0; r < 4; ++r) {
                        int row = rbase + mf * 16 + r;
                        if (row < n) outp[(size_t)row * 128 + col] = acc[mf][r] + bb;
                    }
            } else {
                const int voff = (y == 2) ? 128 : 0;
#pragma unroll
                for (int mf = 0; mf < 2; ++mf)
#pragma unroll
                    for (int r = 0; r < 4; ++r) {
                        int row = rbase + mf * 16 + r;
                        if (row < n)
                            okv[(size_t)row * 256 + voff + col] = bf16rne(acc[mf][r] + bb);
                    }
            }
        }
    }
}

// ---------------------------------------------------------------------------
// Per-target edge attention, online softmax. Two 32-lane halves per wave, each
// owning one edge (4 feats/lane): 5-stage reduce per 2 edges, halved softmax
// scalar cost, single kv base address per edge; states merged via shfl_xor(32).
// Guarded prefetch (no wasted tail gathers), 2-chunk pipeline (8 loads in
// flight per wave).
// ---------------------------------------------------------------------------
__global__ __launch_bounds__(256) void attn_kernel(
    const float* __restrict__ q, const unsigned short* __restrict__ kv,
    const int* __restrict__ rowptr, const int* __restrict__ esrc,
    float* __restrict__ h2, int n) {
    int wid = (blockIdx.x * blockDim.x + threadIdx.x) >> 6;
    int lane = threadIdx.x & 63;
    if (wid >= n) return;
    const int g = lane >> 5;       // half id: edge j+g
    const int f0 = (lane & 31) * 4;
    float4 qv = *(const float4*)(q + (size_t)wid * 128 + f0);
    const float scale = 0.08838834764831845f;  // 1/sqrt(128)
    int beg = rowptr[wid], end = rowptr[wid + 1];
    if (beg == end) return;  // no in-edges: h2 stays = skip term (matches ref)
    float m = -3.402823466e38f, ssum = 0.f;
    float a0 = 0.f, a1 = 0.f, a2 = 0.f, a3 = 0.f;

#define FETCH(J, KU, VU) {                                                   \
        int jj = (J) + g;                                                    \
        if (jj < end) {                                                      \
            int s = esrc[jj];                                                \
            const unsigned short* p = kv + (size_t)s * 256 + f0;             \
            KU = *(const uint2*)p;                                           \
            VU = *(const uint2*)(p + 128);                                   \
        } else { KU.x = 0u; KU.y = 0u; VU.x = 0u; VU.y = 0u; } }

#define PROC(J, KU, VU) {                                                    \
        float kx0 = __uint_as_float(KU.x << 16);                             \
        float kx1 = __uint_as_float(KU.x & 0xFFFF0000u);                     \
        float kx2 = __uint_as_float(KU.y << 16);                             \
        float kx3 = __uint_as_float(KU.y & 0xFFFF0000u);                     \
        float d = qv.x * kx0 + qv.y * kx1 + qv.z * kx2 + qv.w * kx3;         \
        d += __shfl_xor(d, 1);  d += __shfl_xor(d, 2);  d += __shfl_xor(d, 4); \
        d += __shfl_xor(d, 8);  d += __shfl_xor(d, 16);                      \
        d *= scale;                                                          \
        if ((J) + g < end) {                                                 \
            if (d > m) {                                                     \
                float r = __expf(m - d);                                     \
                ssum *= r; a0 *= r; a1 *= r; a2 *= r; a3 *= r; m = d;        \
            }                                                                \
            float w = __expf(d - m);                                         \
            ssum += w;                                                       \
            a0 += w * __uint_as_float(VU.x << 16);                           \
            a1 += w * __uint_as_float(VU.x & 0xFFFF0000u);                   \
            a2 += w * __uint_as_float(VU.y << 16);                           \
            a3 += w * __uint_as_float(VU.y & 0xFFFF0000u);                   \
        } }

    uint2 kA, vA, kB, vB;
    FETCH(beg, kA, vA);
    FETCH(beg + 2, kB, vB);
    int j = beg;
    for (;;) {
        {
            uint2 kN, vN;
            FETCH(j + 4, kN, vN);
            PROC(j, kA, vA);
            kA = kN; vA = vN;
        }
        j += 2; if (j >= end) break;
        {
            uint2 kN, vN;
            FETCH(j + 4, kN, vN);
            PROC(j, kB, vB);
            kB = kN; vB = vN;
        }
        j += 2; if (j >= end) break;
    }
#undef FETCH
#undef PROC

    // merge the two halves' online-softmax states (butterfly, both get result)
    float mo = __shfl_xor(m, 32);
    float m2 = fmaxf(m, mo);
    float fac = __expf(m - m2);      // 0 if this half processed no edges
    ssum *= fac; a0 *= fac; a1 *= fac; a2 *= fac; a3 *= fac;
    ssum += __shfl_xor(ssum, 32);
    a0 += __shfl_xor(a0, 32);
    a1 += __shfl_xor(a1, 32);
    a2 += __shfl_xor(a2, 32);
    a3 += __shfl_xor(a3, 32);
    if (lane < 32) {
        float inv = 1.f / ssum;
        float4* o = (float4*)(h2 + (size_t)wid * 128 + f0);
        float4 cur = *o;
        cur.x += a0 * inv;
        cur.y += a1 * inv;
        cur.z += a2 * inv;
        cur.w += a3 * inv;
        *o = cur;
    }
}

// ---------------------------------------------------------------------------
// BatchNorm stats (apply fused into gemm / pool)
// ---------------------------------------------------------------------------
__global__ __launch_bounds__(256) void bn_stats(const float* __restrict__ h2,
                                                float* __restrict__ psum,
                                                float* __restrict__ psq, int n) {
    int f = threadIdx.x & 127;
    int rp = threadIdx.x >> 7;
    float s = 0.f, s2 = 0.f;
    for (int r = blockIdx.x * 2 + rp; r < n; r += gridDim.x * 2) {
        float x = h2[(size_t)r * 128 + f];
        s += x;
        s2 += x * x;
    }
    __shared__ float sm[256], sm2[256];
    sm[threadIdx.x] = s;
    sm2[threadIdx.x] = s2;
    __syncthreads();
    if (rp == 0) {
        psum[blockIdx.x * 128 + f] = sm[f] + sm[128 + f];
        psq[blockIdx.x * 128 + f] = sm2[f] + sm2[128 + f];
    }
}

__global__ __launch_bounds__(512) void bn_finalize(const float* __restrict__ psum,
                                                   const float* __restrict__ psq,
                                                   const float* __restrict__ g,
                                                   const float* __restrict__ b,
                                                   float* __restrict__ scale,
                                                   float* __restrict__ shift, int n) {
    int f = threadIdx.x & 127, part = threadIdx.x >> 7;
    float s = 0.f, s2 = 0.f;
#pragma unroll 4
    for (int i = part; i < 256; i += 4) {
        s += psum[i * 128 + f];
        s2 += psq[i * 128 + f];
    }
    __shared__ float sa[512], sb[512];
    sa[threadIdx.x] = s;
    sb[threadIdx.x] = s2;
    __syncthreads();
    if (part == 0) {
        s = sa[f] + sa[128 + f] + sa[256 + f] + sa[384 + f];
        s2 = sb[f] + sb[128 + f] + sb[256 + f] + sb[384 + f];
        float inv_n = 1.f / (float)n;
        float mu = s * inv_n;
        float var = s2 * inv_n - mu * mu;
        float sc = g[f] * rsqrtf(var + 1e-5f);
        scale[f] = sc;
        shift[f] = b[f] - mu * sc;
    }
}

// ---------------------------------------------------------------------------
// Pool (fused last BN+ReLU) + head
// ---------------------------------------------------------------------------
__global__ __launch_bounds__(256) void pool_kernel(const float* __restrict__ h,
                                                   const float* __restrict__ bnsc,
                                                   const float* __restrict__ bnsh,
                                                   const int* __restrict__ batch,
                                                   float* __restrict__ pooled, int n) {
    int g = blockIdx.x;
    int lo = 0, hi = n;
    while (lo < hi) { int mid = (lo + hi) >> 1; if (batch[mid] < g) lo = mid + 1; else hi = mid; }
    int start = lo;
    lo = start; hi = n;
    while (lo < hi) { int mid = (lo + hi) >> 1; if (batch[mid] < g + 1) lo = mid + 1; else hi = mid; }
    int end = lo;
    int f = threadIdx.x & 127, rp = threadIdx.x >> 7;
    float sc = bnsc[f], sh = bnsh[f];
    float s = 0.f;
    for (int r = start + rp; r < end; r += 2)
        s += fmaxf(0.f, fmaf(h[(size_t)r * 128 + f], sc, sh));
    __shared__ float sm[256];
    sm[threadIdx.x] = s;
    __syncthreads();
    if (rp == 0) {
        float tot = sm[f] + sm[128 + f];
        float cnt = (float)(end - start);
        pooled[g * 128 + f] = tot / fmaxf(cnt, 1.f);
    }
}

__global__ void head_kernel(const float* __restrict__ pooled, const float* __restrict__ W,
                            const float* __restrict__ bias, float* __restrict__ out) {
    int g = blockIdx.x;
    int lane = threadIdx.x;  // 64
    float p0 = pooled[g * 128 + lane];
    float p1 = pooled[g * 128 + 64 + lane];
#pragma unroll
    for (int c = 0; c < C_CLASSES; ++c) {
        float d = p0 * W[lane * C_CLASSES + c] + p1 * W[(64 + lane) * C_CLASSES + c];
#pragma unroll
        for (int off = 32; off; off >>= 1) d += __shfl_xor(d, off);
        if (lane == 0) out[g * C_CLASSES + c] = d + bias[c];
    }
}

// ---------------------------------------------------------------------------
extern "C" void kernel_launch(void* const* d_in, const int* in_sizes, int n_in,
                              void* d_out, int out_size, void* d_ws, size_t ws_size,
                              hipStream_t stream) {
    const int N = in_sizes[0] / IN_DIM;       // 100000
    const int E = in_sizes[1] / 2;            // 600000

    const float* x     = (const float*)d_in[0];
    const int* ei      = (const int*)d_in[1];
    const int* src     = ei;
    const int* dst     = ei + E;
    const int* batch   = (const int*)d_in[2];
    const float* Wq1 = (const float*)d_in[3],  *bq1 = (const float*)d_in[4];
    const float* Wk1 = (const float*)d_in[5],  *bk1 = (const float*)d_in[6];
    const float* Wv1 = (const float*)d_in[7],  *bv1 = (const float*)d_in[8];
    const float* Ws1 = (const float*)d_in[9],  *bs1 = (const float*)d_in[10];
    const float* bn1g = (const float*)d_in[11], *bn1b = (const float*)d_in[12];
    const float* Wq = (const float*)d_in[13], *bq = (const float*)d_in[14];
    const float* Wk = (const float*)d_in[15], *bk = (const float*)d_in[16];
    const float* Wv = (const float*)d_in[17], *bv = (const float*)d_in[18];
    const float* Ws = (const float*)d_in[19], *bs = (const float*)d_in[20];
    const float* bng = (const float*)d_in[21], *bnb = (const float*)d_in[22];
    const float* linW = (const float*)d_in[23], *linb = (const float*)d_in[24];
    float* out = (float*)d_out;

    const int strips = (N + 31) / 32;         // 3125 (N % 32 == 0)

    // workspace layout
    char* w = (char*)d_ws;
    auto alloc = [&](size_t bytes) -> char* {
        char* p = w;
        w += (bytes + 255) & ~(size_t)255;
        return p;
    };
    const size_t NH = (size_t)N * H_DIM;
    float* q     = (float*)alloc(NH * 4);
    float* convA = (float*)alloc(NH * 4);
    float* convB = (float*)alloc(NH * 4);
    unsigned short* kv16 = (unsigned short*)alloc((size_t)N * 256 * 2);
    unsigned short* WF   = (unsigned short*)alloc((size_t)(65536 + 12 * 32768) * 2);
    float* psum = (float*)alloc(256 * 128 * 4);
    float* psq  = (float*)alloc(256 * 128 * 4);
    float* bnsc = (float*)alloc(128 * 4);
    float* bnsh = (float*)alloc(128 * 4);
    float* pooled = (float*)alloc(G_GRAPHS * H_DIM * 4);
    int* deg    = (int*)alloc((size_t)N * 4);
    int* rowptr = (int*)alloc((size_t)(N + 1) * 4);
    int* erank  = (int*)alloc((size_t)E * 4);
    int* esrc   = (int*)alloc((size_t)E * 4);
    int* bsum   = (int*)alloc(((size_t)(N + 255) / 256) * 4);

    const int nblk = (N + 255) / 256;
    const int egrid = (E + 255) / 256;

    // ---- CSR build + all weight prep (independent, up-front)
    hipMemsetAsync(deg, 0, (size_t)N * 4, stream);
    count_deg<<<egrid, 256, 0, stream>>>(dst, deg, erank, E);
    prep_w64<<<dim3(4, 4), 256, 0, stream>>>(Wq1, Wk1, Wv1, Ws1, WF);
    prep_w128<<<dim3(8, 12), 256, 0, stream>>>(Wq, Wk, Wv, Ws, WF);
    scan1<<<nblk, 256, 0, stream>>>(deg, rowptr, bsum, N);
    scan2<<<1, 512, 0, stream>>>(bsum, nblk);
    scan3<<<nblk, 256, 0, stream>>>(rowptr, bsum, N);
    scatter_edges<<<egrid, 256, 0, stream>>>(src, dst, rowptr, erank, esrc, E);

    const int attn_blocks = (N + 3) / 4;
    const int gemm_blocks = (strips + 3) / 4;

    // ---- layer 1 (K=64, raw input, no BN)
    gemm_fused<IN_DIM, false><<<gemm_blocks, 256, 0, stream>>>(
        x, WF, N, strips, nullptr, nullptr, bq1, bk1, bv1, bs1, q, kv16, convA);
    attn_kernel<<<attn_blocks, 256, 0, stream>>>(q, kv16, rowptr, esrc, convA, N);
    bn_stats<<<256, 256, 0, stream>>>(convA, psum, psq, N);
    bn_finalize<<<1, 512, 0, stream>>>(psum, psq, bn1g, bn1b, bnsc, bnsh, N);

    // ---- layers 2..4 (K=128, prev BN+ReLU fused into gemm A-load)
    float* cur = convA;
    float* nxt = convB;
    for (int i = 0; i < L_LAYERS; ++i) {
        const size_t bo = (size_t)i * H_DIM;
        const unsigned short* WFl = WF + 65536 + (size_t)i * 4 * 32768;
        gemm_fused<H_DIM, true><<<gemm_blocks, 256, 0, stream>>>(
            cur, WFl, N, strips, bnsc, bnsh, bq + bo, bk + bo, bv + bo, bs + bo,
            q, kv16, nxt);
        attn_kernel<<<attn_blocks, 256, 0, stream>>>(q, kv16, rowptr, esrc, nxt, N);
        bn_stats<<<256, 256, 0, stream>>>(nxt, psum, psq, N);
        bn_finalize<<<1, 512, 0, stream>>>(psum, psq, bng + bo, bnb + bo, bnsc, bnsh, N);
        float* t = cur; cur = nxt; nxt = t;
    }

    // ---- pool (fused last BN+ReLU) + head
    pool_kernel<<<G_GRAPHS, 256, 0, stream>>>(cur, bnsc, bnsh, batch, pooled, N);
    head_kernel<<<G_GRAPHS, 64, 0, stream>>>(pooled, linW, linb, out);
}